// Round 9
// baseline (202.782 us; speedup 1.0000x reference)
//
#include <hip/hip_runtime.h>
#include <hip/hip_bf16.h>

#define B_  2
#define T_  2048
#define NH_ 16
#define HS_ 64
#define C_  1024
#define SCL_ 128              // EMA chunk length
#define SCN_ (T_ / SCL_)      // 16 chunks
#define NT_  (T_ / 64)        // 32 key/query tiles
#define TEL_ 4096             // elements per 64x64 tile

typedef __attribute__((ext_vector_type(8))) short bf16x8;
typedef __attribute__((ext_vector_type(4))) float f32x4;

__device__ inline int pack_bf16(float a, float b) {
  union { __hip_bfloat16 h; unsigned short u; } ua, ub;
  ua.h = __float2bfloat16(a);
  ub.h = __float2bfloat16(b);
  return (int)(((unsigned)ub.u << 16) | (unsigned)ua.u);
}

// async global->LDS 16B: global ptr is PER-LANE; LDS dest must equal
// wave-uniform base + lane*16. Callers pass per-lane g AND l = base+lane*16.
__device__ inline void gl_lds16(const __hip_bfloat16* g, __hip_bfloat16* l) {
  __builtin_amdgcn_global_load_lds(
      (const __attribute__((address_space(1))) unsigned int*)g,
      (__attribute__((address_space(3))) unsigned int*)l, 16, 0, 0);
}

// ---------------------------------------------------------------------------
// prep1: fused {3x weight transpose} (blocks [0,768) -- LONG blocks first so
// their latency overlaps the streaming cvt flood) + {fp32->bf16 x conversion}
// (blocks [768, 2816)).
// ---------------------------------------------------------------------------
__global__ __launch_bounds__(256) void prep1_kernel(const float* __restrict__ x,
                                                    const float* __restrict__ W_la,
                                                    const float* __restrict__ W_v,
                                                    const float* __restrict__ W_proj,
                                                    __hip_bfloat16* __restrict__ x16,
                                                    __hip_bfloat16* __restrict__ Wcat,
                                                    __hip_bfloat16* __restrict__ WprojT) {
  __shared__ __hip_bfloat16 tile[64][66];
  const int bid = (int)blockIdx.x;
  if (bid >= 768) {
    const int i = ((bid - 768) * 256 + (int)threadIdx.x) * 8;
    const float4 a = *reinterpret_cast<const float4*>(x + i);
    const float4 b = *reinterpret_cast<const float4*>(x + i + 4);
    union { int s[4]; int4 v; } u;
    u.s[0] = pack_bf16(a.x, a.y);
    u.s[1] = pack_bf16(a.z, a.w);
    u.s[2] = pack_bf16(b.x, b.y);
    u.s[3] = pack_bf16(b.z, b.w);
    *reinterpret_cast<int4*>(x16 + i) = u.v;
    return;
  }
  const int id = bid;               // 0..767
  const int z = id >> 8;            // 0..2
  const int rem = id & 255;
  const int bx = rem & 15, by = rem >> 4;
  const float* W = (z == 0) ? W_la : (z == 1) ? W_v : W_proj;
  __hip_bfloat16* WT = (z == 2) ? WprojT : Wcat + (size_t)z * C_ * C_;
  const int w = threadIdx.x >> 6, l = threadIdx.x & 63;
  const int n0 = bx * 64, k0 = by * 64;
#pragma unroll
  for (int r = 0; r < 16; ++r) {
    const int k = k0 + w * 16 + r;
    tile[w * 16 + r][l] = __float2bfloat16(W[(size_t)k * C_ + n0 + l]);
  }
  __syncthreads();
#pragma unroll
  for (int r = 0; r < 16; ++r) {
    const int nn = w * 16 + r;
    WT[(size_t)(n0 + nn) * C_ + k0 + l] = tile[l][nn];
  }
}

// ---------------------------------------------------------------------------
// Combined input GEMM: [xl | xv] = x16(4096x1024) @ Wcat(2048x1024)^T.
// 2-phase double-buffered pipeline, counted vmcnt, raw s_barrier.
// ---------------------------------------------------------------------------
__global__ __launch_bounds__(256) void gemm_in_kernel(const __hip_bfloat16* __restrict__ A,
                                                      const __hip_bfloat16* __restrict__ BT,
                                                      float* __restrict__ C0,
                                                      float* __restrict__ C1) {
  __shared__ __hip_bfloat16 As[2 * 128 * 32];
  __shared__ __hip_bfloat16 Bs[2 * 128 * 32];
  const int tid = threadIdx.x;
  const int m0 = blockIdx.y * 128, n0 = blockIdx.x * 128;
  const int w = tid >> 6, l = tid & 63;
  const int n = l & 15, kg = l >> 4;
  const int m0w = (w & 1) * 64, n0w = (w >> 1) * 64;

  const int r0 = tid >> 2, o0 = (tid & 3) * 8;
  const __hip_bfloat16* ag0 = A + (size_t)(m0 + r0) * C_ + o0;
  const __hip_bfloat16* ag1 = A + (size_t)(m0 + 64 + r0) * C_ + o0;
  const __hip_bfloat16* bg0 = BT + (size_t)(n0 + r0) * C_ + o0;
  const __hip_bfloat16* bg1 = BT + (size_t)(n0 + 64 + r0) * C_ + o0;

  f32x4 acc[4][4];
#pragma unroll
  for (int i = 0; i < 4; ++i)
#pragma unroll
    for (int j = 0; j < 4; ++j) acc[i][j] = f32x4{0.f, 0.f, 0.f, 0.f};

  auto stage = [&](int kk, int buf) {
    __hip_bfloat16* a = As + buf * 4096;
    __hip_bfloat16* b = Bs + buf * 4096;
    gl_lds16(ag0 + kk, a + tid * 8);
    gl_lds16(ag1 + kk, a + 2048 + tid * 8);
    gl_lds16(bg0 + kk, b + tid * 8);
    gl_lds16(bg1 + kk, b + 2048 + tid * 8);
  };

  stage(0, 0);
  int cur = 0;
  for (int k0 = 0; k0 < C_; k0 += 32) {
    asm volatile("" ::: "memory");
    __builtin_amdgcn_s_barrier();   // buf[cur^1] readers (iter-1) done
    asm volatile("" ::: "memory");
    if (k0 + 32 < C_) {
      stage(k0 + 32, cur ^ 1);
      asm volatile("s_waitcnt vmcnt(4)" ::: "memory");  // older 4 (this tile) landed
    } else {
      asm volatile("s_waitcnt vmcnt(0)" ::: "memory");
    }
    __builtin_amdgcn_s_barrier();   // all waves' tile-k0 DMAs landed
    asm volatile("" ::: "memory");

    const __hip_bfloat16* Ab = As + cur * 4096;
    const __hip_bfloat16* Bb = Bs + cur * 4096;
    bf16x8 af[4], bf[4];
#pragma unroll
    for (int ms = 0; ms < 4; ++ms)
      af[ms] = *reinterpret_cast<const bf16x8*>(Ab + (m0w + ms * 16 + n) * 32 + kg * 8);
#pragma unroll
    for (int ns = 0; ns < 4; ++ns)
      bf[ns] = *reinterpret_cast<const bf16x8*>(Bb + (n0w + ns * 16 + n) * 32 + kg * 8);
#pragma unroll
    for (int ms = 0; ms < 4; ++ms)
#pragma unroll
      for (int ns = 0; ns < 4; ++ns)
        acc[ms][ns] = __builtin_amdgcn_mfma_f32_16x16x32_bf16(af[ms], bf[ns], acc[ms][ns], 0, 0, 0);
    cur ^= 1;
  }

  float* Cb = (n0 < C_) ? C0 : C1;
  const int nc = (n0 < C_) ? n0 : n0 - C_;
#pragma unroll
  for (int ms = 0; ms < 4; ++ms) {
#pragma unroll
    for (int r = 0; r < 4; ++r) {
      const int row = m0 + m0w + ms * 16 + kg * 4 + r;
      float* cp = Cb + (size_t)row * C_ + nc + n0w + n;
#pragma unroll
      for (int ns = 0; ns < 4; ++ns) cp[ns * 16] = acc[ms][ns][r];
    }
  }
}

// ---------------------------------------------------------------------------
// Projection GEMM: out = y16(4096x1024) @ WprojT(1024x1024)^T, fp32 out.
// ---------------------------------------------------------------------------
__global__ __launch_bounds__(256) void gemm_proj_kernel(const __hip_bfloat16* __restrict__ A,
                                                        const __hip_bfloat16* __restrict__ BT,
                                                        float* __restrict__ Cout) {
  __shared__ __hip_bfloat16 As[2 * 64 * 32];
  __shared__ __hip_bfloat16 Bs[2 * 128 * 32];
  const int tid = threadIdx.x;
  const int m0 = blockIdx.y * 64, n0 = blockIdx.x * 128;
  const int w = tid >> 6, l = tid & 63;
  const int n = l & 15, kg = l >> 4;

  const int r0 = tid >> 2, o0 = (tid & 3) * 8;
  const __hip_bfloat16* ag = A + (size_t)(m0 + r0) * C_ + o0;
  const __hip_bfloat16* bg0 = BT + (size_t)(n0 + r0) * C_ + o0;
  const __hip_bfloat16* bg1 = BT + (size_t)(n0 + 64 + r0) * C_ + o0;

  f32x4 acc[4][2];
#pragma unroll
  for (int i = 0; i < 4; ++i)
#pragma unroll
    for (int j = 0; j < 2; ++j) acc[i][j] = f32x4{0.f, 0.f, 0.f, 0.f};

  auto stage = [&](int kk, int buf) {
    __hip_bfloat16* a = As + buf * 2048;
    __hip_bfloat16* b = Bs + buf * 4096;
    gl_lds16(ag + kk, a + tid * 8);
    gl_lds16(bg0 + kk, b + tid * 8);
    gl_lds16(bg1 + kk, b + 2048 + tid * 8);
  };

  stage(0, 0);
  int cur = 0;
  for (int k0 = 0; k0 < C_; k0 += 32) {
    asm volatile("" ::: "memory");
    __builtin_amdgcn_s_barrier();
    asm volatile("" ::: "memory");
    if (k0 + 32 < C_) {
      stage(k0 + 32, cur ^ 1);
      asm volatile("s_waitcnt vmcnt(3)" ::: "memory");
    } else {
      asm volatile("s_waitcnt vmcnt(0)" ::: "memory");
    }
    __builtin_amdgcn_s_barrier();
    asm volatile("" ::: "memory");

    const __hip_bfloat16* Ab = As + cur * 2048;
    const __hip_bfloat16* Bb = Bs + cur * 4096;
    bf16x8 af[4], bf[2];
#pragma unroll
    for (int ms = 0; ms < 4; ++ms)
      af[ms] = *reinterpret_cast<const bf16x8*>(Ab + (ms * 16 + n) * 32 + kg * 8);
#pragma unroll
    for (int ns = 0; ns < 2; ++ns)
      bf[ns] = *reinterpret_cast<const bf16x8*>(Bb + (w * 32 + ns * 16 + n) * 32 + kg * 8);
#pragma unroll
    for (int ms = 0; ms < 4; ++ms)
#pragma unroll
      for (int ns = 0; ns < 2; ++ns)
        acc[ms][ns] = __builtin_amdgcn_mfma_f32_16x16x32_bf16(af[ms], bf[ns], acc[ms][ns], 0, 0, 0);
    cur ^= 1;
  }

#pragma unroll
  for (int ms = 0; ms < 4; ++ms) {
#pragma unroll
    for (int r = 0; r < 4; ++r) {
      const int row = m0 + ms * 16 + kg * 4 + r;
      float* cp = Cout + (size_t)row * C_ + n0 + w * 32 + n;
#pragma unroll
      for (int ns = 0; ns < 2; ++ns) cp[ns * 16] = acc[ms][ns][r];
    }
  }
}

// ---------------------------------------------------------------------------
// prep2: EMA blocks FIRST (bid [0,512)) so the latency-bound, 2-round-trip
// EMA blocks start at t=0 and overlap with the 1024 plentiful vprep blocks
// (bid [512,1536)) -- kills the low-occupancy EMA tail (R7: 28.9% occ).
// EMA additionally uses T14 register double-stage: BOTH chunks' 8xfloat4
// loads issued up front (16 in flight), warmup written to LDS + scanned
// while own-chunk loads are still landing -> one latency round-trip, not two.
// 4-wave parallel scan + truncated carry (alpha^128 <= 1.4e-6) as before.
// ---------------------------------------------------------------------------
__global__ __launch_bounds__(256) void prep2_kernel(const float* __restrict__ xv,
                                                    const float* __restrict__ xl,
                                                    __hip_bfloat16* __restrict__ vt,
                                                    __hip_bfloat16* __restrict__ kb16,
                                                    const float* __restrict__ value_beta,
                                                    const float* __restrict__ v_coef,
                                                    const float* __restrict__ la_coef,
                                                    const float* __restrict__ kernel_beta) {
  __shared__ float4 smem4[2048];   // 32 KB, shared by both paths
  __shared__ float carrW[4][64];   // warmup carries  (1 KB)
  __shared__ float carrS[4][64];   // own-chunk carries (1 KB)
  const int bid = (int)blockIdx.x;
  if (bid >= 512) {
    // ---- vprep ----
    __hip_bfloat16 (*tile)[66] = reinterpret_cast<__hip_bfloat16(*)[66]>(smem4);
    const int vb_id = bid - 512;
    const int tc = vb_id % NT_;
    const int bh = vb_id / NT_;
    const int h = bh % NH_, b = bh / NH_;
    const int t0 = tc * 64;
    const int w = threadIdx.x >> 6, l = threadIdx.x & 63;

    const float c = v_coef[h];
    const float vb = expf(value_beta[h] * 10.0f);

    for (int r = 0; r < 16; ++r) {
      const int tl = w * 16 + r;
      const int t = t0 + tl;
      const float* base = xv + ((size_t)b * T_ + t) * C_ + h * HS_ + l;
      const float cu = base[0];
      const float nxt = (t + 1 < T_) ? base[C_] : 0.0f;
      float val = nxt * (1.0f - c) + cu * c;
      float ssum = val * val;
#pragma unroll
      for (int m = 32; m; m >>= 1) ssum += __shfl_xor(ssum, m);
      tile[tl][l] = __float2bfloat16(val * (vb / sqrtf(ssum)));
    }
    __syncthreads();
    __hip_bfloat16* vtb = vt + (size_t)(bh * NT_ + tc) * TEL_;
    const int kk = l >> 3, j = l & 7;  // l = key
    for (int rr = 0; rr < 16; ++rr) {
      const int hs = w * 16 + rr;
      vtb[(kk * 64 + hs) * 8 + j] = tile[l][hs];
    }
    return;
  }
  // ---- EMA: reg double-stage + 4-wave scan + norm + kb16 slot emit ----
  {
    float* buf = reinterpret_cast<float*>(smem4);  // 128 x 64 fp32 = 32 KB
    const int c = bid % SCN_;
    const int bh = bid / SCN_;
    const int b = bh / NH_, h = bh % NH_;
    const int tid = threadIdx.x;
    const int w = tid >> 6, l = tid & 63;

    const float alpha = la_coef[h];
    const float onema = 1.0f - alpha;
    const float a32 = __powf(alpha, 32.0f);
    const float kbs = expf(fminf(kernel_beta[h] * 10.0f, 5.0f));
    const float4* src4 = reinterpret_cast<const float4*>(xl + (size_t)b * T_ * C_ + h * HS_);
    float4* buf4 = reinterpret_cast<float4*>(buf);

    const int t0 = c * SCL_;
    // issue BOTH chunks' loads up front (T14): 16 float4 in flight
    float4 rw[8], ro[8];
    if (c > 0) {
      const int t0p = (c - 1) * SCL_;
#pragma unroll
      for (int i = 0; i < 8; ++i) {
        const int ix = tid + i * 256;
        rw[i] = src4[(size_t)(t0p + (ix >> 4)) * (C_ / 4) + (ix & 15)];
      }
    }
#pragma unroll
    for (int i = 0; i < 8; ++i) {
      const int ix = tid + i * 256;
      ro[i] = src4[(size_t)(t0 + (ix >> 4)) * (C_ / 4) + (ix & 15)];
    }

    // local zero-init scan of this wave's 32 rows; returns carry (lane=dim)
    auto localCarry = [&]() -> float {
      float A = 0.0f;
      const float* bp = buf + (w * 32) * HS_ + l;
#pragma unroll 8
      for (int tt = 0; tt < 32; ++tt) A = alpha * A + onema * bp[tt * HS_];
      return A;
    };

    float W = 0.0f;  // combined carry of previous chunk (truncated history)
    if (c > 0) {
#pragma unroll
      for (int i = 0; i < 8; ++i) {
        const int ix = tid + i * 256;
        buf4[(ix >> 4) * 16 + (ix & 15)] = rw[i];
      }
      __syncthreads();
      carrW[w][l] = localCarry();
      __syncthreads();   // carries written AND all buf reads complete
      W = ((carrW[0][l] * a32 + carrW[1][l]) * a32 + carrW[2][l]) * a32 + carrW[3][l];
    }
#pragma unroll
    for (int i = 0; i < 8; ++i) {
      const int ix = tid + i * 256;
      buf4[(ix >> 4) * 16 + (ix & 15)] = ro[i];
    }
    __syncthreads();
    carrS[w][l] = localCarry();
    __syncthreads();
    // prefix state for this wave: P_w = carry of all rows before row 32w
    float P = W;
#pragma unroll
    for (int j2 = 0; j2 < 3; ++j2)
      if (j2 < w) P = carrS[j2][l] + a32 * P;  // wave-uniform branch
    // pass 2: re-scan with init P -> exact value; fuse norm + emit
    __hip_bfloat16* kt = kb16 + (size_t)bh * NT_ * TEL_;
    const int g = l >> 3, j = l & 7;
    const float* bp = buf + (w * 32) * HS_ + l;
    float A = P;
    for (int rr = 0; rr < 32; ++rr) {
      A = alpha * A + onema * bp[rr * HS_];
      float ss = A * A;
#pragma unroll
      for (int m = 32; m; m >>= 1) ss += __shfl_xor(ss, m);
      const int t = t0 + w * 32 + rr;
      const int tile = t >> 6, key = t & 63;
      kt[(size_t)tile * TEL_ + (g * 64 + key) * 8 + j] = __float2bfloat16(A * (kbs / sqrtf(ss)));
    }
  }
}

// ---------------------------------------------------------------------------
// MFMA flash attention, V-DIRECT + 2-TILE PAIRED iterations (R5 config:
// best measured). Ks = 2 buf x 2 tiles (32 KB) + Ps 8 KB = 40960 B ->
// 4 blocks/CU. Per pair: 2 barriers serve TWO 64-key tiles; tile B sync-free.
// vmcnt: outstanding at wait = oldK(4) + vfA(8) + newK(c) -> vmcnt(8+c).
// ---------------------------------------------------------------------------
__global__ __launch_bounds__(256, 4) void attn_mfma_kernel(
    const __hip_bfloat16* __restrict__ kb,   // (BH, NT, g, key, 8) slot tiles
    const __hip_bfloat16* __restrict__ vt,   // (BH, NT, kk, hs, 8) slot tiles
    __hip_bfloat16* __restrict__ y) {        // (B, T, C) bf16
  __shared__ __hip_bfloat16 Ks[2][2 * TEL_]; // 32 KB: [buf][tile0|tile1]
  __shared__ __hip_bfloat16 Ps[4][16 * 64];  // 8 KB, XOR-swizzled granules

  const int id = (int)blockIdx.x;
  const int xcd = id & 7;
  const int s = id >> 3;                 // 0..127
  const int bh = xcd + 8 * (s & 3);      // 32 bh, grouped 4 per XCD
  const int v = s >> 2;                  // 0..31
  const int qt = (v < 16) ? (31 - v) : (v - 16);  // balanced bijection
  const int b = bh / NH_, h = bh % NH_;
  const int q0 = qt * 64;
  const int w = threadIdx.x >> 6;
  const int l = threadIdx.x & 63;
  const int n = l & 15;
  const int kg = l >> 4;
  const int qq = w * 16 + n;             // within-tile query index
  const int query = q0 + qq;
  const int lo = l * 8;                  // per-lane 16B offset (elements)
  const int tb = bh * NT_;
  const int so = w * 1024 + lo;          // per-wave stage offset (elements)

  // Q B-fragments from global slot tile (once)
  bf16x8 qf0, qf1;
  {
    const __hip_bfloat16* qtile = kb + (size_t)(tb + qt) * TEL_;
    qf0 = *reinterpret_cast<const bf16x8*>(qtile + (kg * 64 + qq) * 8);
    qf1 = *reinterpret_cast<const bf16x8*>(qtile + ((kg + 4) * 64 + qq) * 8);
  }
  // per-lane V fragment base: fragment (ks,mo) at vbase + ks*2048 + mo*128
  const __hip_bfloat16* vbase = vt + (size_t)tb * TEL_ + (kg * 64 + n) * 8;

  f32x4 accO[4];
#pragma unroll
  for (int i = 0; i < 4; ++i) accO[i] = f32x4{0.f, 0.f, 0.f, 0.f};
  float l_acc = 0.0f;

  __hip_bfloat16* Pw = Ps[w];
  int* Pwi = reinterpret_cast<int*>(Pw);

  auto stage2 = [&](int j0, int buf) {   // 4 DMAs: tiles j0, j0+1
    const size_t tg = (size_t)(tb + j0) * TEL_;
    __hip_bfloat16* Kb = &Ks[buf][0];
    gl_lds16(kb + tg + so, Kb + so);
    gl_lds16(kb + tg + so + 512, Kb + so + 512);
    gl_lds16(kb + tg + TEL_ + so, Kb + TEL_ + so);
    gl_lds16(kb + tg + TEL_ + so + 512, Kb + TEL_ + so + 512);
  };
  auto stage1 = [&](int j0, int buf) {   // 2 DMAs: tile j0 into half 0
    const size_t tg = (size_t)(tb + j0) * TEL_;
    __hip_bfloat16* Kb = &Ks[buf][0];
    gl_lds16(kb + tg + so, Kb + so);
    gl_lds16(kb + tg + so + 512, Kb + so + 512);
  };
  auto loadV = [&](int jt, bf16x8 (&vf)[2][4]) {
    const __hip_bfloat16* vp = vbase + (size_t)jt * TEL_;
#pragma unroll
    for (int ks = 0; ks < 2; ++ks)
#pragma unroll
      for (int mo = 0; mo < 4; ++mo)
        vf[ks][mo] = *reinterpret_cast<const bf16x8*>(vp + ks * 2048 + mo * 128);
  };
  auto computeS = [&](const __hip_bfloat16* Kc, f32x4 (&accS)[4]) {
    __builtin_amdgcn_s_setprio(1);
#pragma unroll
    for (int ms = 0; ms < 4; ++ms) {
      bf16x8 a0 = *reinterpret_cast<const bf16x8*>(Kc + (kg * 64 + ms * 16 + n) * 8);
      bf16x8 a1 = *reinterpret_cast<const bf16x8*>(Kc + ((kg + 4) * 64 + ms * 16 + n) * 8);
      f32x4 z{0.f, 0.f, 0.f, 0.f};
      z = __builtin_amdgcn_mfma_f32_16x16x32_bf16(a0, qf0, z, 0, 0, 0);
      accS[ms] = __builtin_amdgcn_mfma_f32_16x16x32_bf16(a1, qf1, z, 0, 0, 0);
    }
    __builtin_amdgcn_s_setprio(0);
  };
  auto softmaxStore = [&](const f32x4 (&accS)[4], bool diag) {
    if (!diag) {
#pragma unroll
      for (int ms = 0; ms < 4; ++ms) {
        const float p0 = __expf(accS[ms][0]), p1 = __expf(accS[ms][1]);
        const float p2 = __expf(accS[ms][2]), p3 = __expf(accS[ms][3]);
        l_acc += p0 + p1 + p2 + p3;
        const int po = n * 32 + (((ms * 4 + kg) ^ n) << 1);
        int2 pw;
        pw.x = pack_bf16(p0, p1);
        pw.y = pack_bf16(p2, p3);
        *reinterpret_cast<int2*>(&Pwi[po]) = pw;
      }
    } else {
#pragma unroll
      for (int ms = 0; ms < 4; ++ms) {
        const int kbase = ms * 16 + kg * 4;
        float p[4];
#pragma unroll
        for (int r = 0; r < 4; ++r) {
          const float e = __expf(accS[ms][r]);
          p[r] = (kbase + r < qq) ? e : 0.0f;
          l_acc += p[r];
        }
        const int po = n * 32 + (((ms * 4 + kg) ^ n) << 1);
        int2 pw;
        pw.x = pack_bf16(p[0], p[1]);
        pw.y = pack_bf16(p[2], p[3]);
        *reinterpret_cast<int2*>(&Pwi[po]) = pw;
      }
    }
  };
  auto pv = [&](const bf16x8 (&vf)[2][4]) {
    __builtin_amdgcn_s_setprio(1);
#pragma unroll
    for (int ks = 0; ks < 2; ++ks) {
      union { ushort4 u[2]; bf16x8 vv; } pr;
      const int ga = (ks * 8 + kg * 2) ^ n;      // granule of keys kg*8+0..3
      const __hip_bfloat16* pp = Pw + n * 64;
      pr.u[0] = *reinterpret_cast<const ushort4*>(pp + ga * 4);
      pr.u[1] = *reinterpret_cast<const ushort4*>(pp + (ga ^ 1) * 4);
#pragma unroll
      for (int mo = 0; mo < 4; ++mo)
        accO[mo] = __builtin_amdgcn_mfma_f32_16x16x32_bf16(vf[ks][mo], pr.vv, accO[mo], 0, 0, 0);
    }
    __builtin_amdgcn_s_setprio(0);
  };

  // prologue: stage first pair (or single) into buf 0
  if (qt >= 1) stage2(0, 0); else stage1(0, 0);

  int cur = 0;
  int jp = 0;
  for (; jp + 1 <= qt; jp += 2) {
    // barrier #1: all waves done reading Ks[cur^1]
    asm volatile("" ::: "memory");
    __builtin_amdgcn_s_barrier();
    asm volatile("" ::: "memory");

    bf16x8 vfA[2][4];
    loadV(jp, vfA);                     // 8 V loads (oldest after oldK)
    asm volatile("" ::: "memory");      // pin V issue before K-DMA

    const int nx = jp + 2;
    if (nx + 1 <= qt) {
      stage2(nx, cur ^ 1);
      asm volatile("s_waitcnt vmcnt(12)" ::: "memory");  // drain oldK(4)
    } else if (nx <= qt) {
      stage1(nx, cur ^ 1);
      asm volatile("s_waitcnt vmcnt(10)" ::: "memory");
    } else {
      asm volatile("s_waitcnt vmcnt(8)" ::: "memory");
    }
    // barrier #2: every wave's pair-K DMAs have landed
    __builtin_amdgcn_s_barrier();
    asm volatile("" ::: "memory");

    // ---- tile A (index jp, never diagonal in pair loop) ----
    f32x4 accS[4];
    computeS(&Ks[cur][0], accS);
    softmaxStore(accS, false);
    pv(vfA);

    asm volatile("" ::: "memory");  // tile A P-reads before tile B P-writes

    // ---- tile B (index jp+1, diag iff == qt); sync-free ----
    bf16x8 vfB[2][4];
    loadV(jp + 1, vfB);             // hidden under S(B)+softmax(B)
    computeS(&Ks[cur][TEL_], accS);
    softmaxStore(accS, jp + 1 == qt);
    pv(vfB);

    cur ^= 1;
  }
  if (jp <= qt) {  // peeled single (diagonal) tile
    asm volatile("" ::: "memory");
    __builtin_amdgcn_s_barrier();
    asm volatile("" ::: "memory");
    bf16x8 vfA[2][4];
    loadV(jp, vfA);
    asm volatile("s_waitcnt vmcnt(8)" ::: "memory");  // drain the 2 oldK
    __builtin_amdgcn_s_barrier();
    asm volatile("" ::: "memory");
    f32x4 accS[4];
    computeS(&Ks[cur][0], accS);
    softmaxStore(accS, true);
    pv(vfA);
  }

  // ---- deferred row reduction + epilogue ----
  l_acc += __shfl_xor(l_acc, 16);
  l_acc += __shfl_xor(l_acc, 32);
  const float inv = (query == 0) ? 0.0f : 1.0f / l_acc;
  __hip_bfloat16* yb = y + ((size_t)b * T_ + query) * C_ + h * HS_;
#pragma unroll
  for (int mo = 0; mo < 4; ++mo) {
    int2 pkd;
    pkd.x = pack_bf16(accO[mo][0] * inv, accO[mo][1] * inv);
    pkd.y = pack_bf16(accO[mo][2] * inv, accO[mo][3] * inv);
    *reinterpret_cast<int2*>(yb + mo * 16 + kg * 4) = pkd;
  }
}

// ---------------------------------------------------------------------------
extern "C" void kernel_launch(void* const* d_in, const int* in_sizes, int n_in,
                              void* d_out, int out_size, void* d_ws, size_t ws_size,
                              hipStream_t stream) {
  const float* x           = (const float*)d_in[0];
  const float* W_la        = (const float*)d_in[1];
  const float* la_coef     = (const float*)d_in[2];
  const float* kernel_beta = (const float*)d_in[3];
  const float* value_beta  = (const float*)d_in[4];
  const float* W_v         = (const float*)d_in[5];
  const float* v_coef      = (const float*)d_in[6];
  const float* W_proj      = (const float*)d_in[7];
  float* out = (float*)d_out;

  char* wsb = (char*)d_ws;
  const size_t MB = 1024u * 1024u;
  __hip_bfloat16* x16    = (__hip_bfloat16*)(wsb);            // 8 MB
  __hip_bfloat16* Wcat   = (__hip_bfloat16*)(wsb + 8 * MB);   // 4 MB (W_laT | W_vT)
  __hip_bfloat16* WprojT = (__hip_bfloat16*)(wsb + 12 * MB);  // 2 MB
  float* xl              = (float*)(wsb + 16 * MB);           // 16 MB
  float* xv              = (float*)(wsb + 32 * MB);           // 16 MB
  __hip_bfloat16* kb16   = (__hip_bfloat16*)(wsb + 48 * MB);  // 8 MB
  __hip_bfloat16* vt16   = (__hip_bfloat16*)(wsb + 56 * MB);  // 8 MB
  __hip_bfloat16* y16    = (__hip_bfloat16*)(wsb + 64 * MB);  // 8 MB (xl still
                                                              //  live during prep2)
  (void)ws_size; (void)in_sizes; (void)n_in; (void)out_size;

  const int M = B_ * T_;

  prep1_kernel<<<dim3(2048 + 768), dim3(256), 0, stream>>>(x, W_la, W_v, W_proj, x16, Wcat, WprojT);
  gemm_in_kernel<<<dim3(2 * C_ / 128, M / 128), dim3(256), 0, stream>>>(x16, Wcat, xl, xv);
  prep2_kernel<<<dim3(512 + 1024), dim3(256), 0, stream>>>(xv, xl, vt16, kb16,
                                                           value_beta, v_coef, la_coef, kernel_beta);
  attn_mfma_kernel<<<dim3(8 * 128), dim3(256), 0, stream>>>(kb16, vt16, y16);
  gemm_proj_kernel<<<dim3(C_ / 128, M / 64), dim3(256), 0, stream>>>(y16, WprojT, out);
}

// Round 10
// 189.848 us; speedup vs baseline: 1.0681x; 1.0681x over previous
//
#include <hip/hip_runtime.h>
#include <hip/hip_bf16.h>

#define B_  2
#define T_  2048
#define NH_ 16
#define HS_ 64
#define C_  1024
#define SCL_ 128              // EMA chunk length
#define SCN_ (T_ / SCL_)      // 16 chunks
#define NT_  (T_ / 64)        // 32 key/query tiles
#define TEL_ 4096             // elements per 64x64 tile

typedef __attribute__((ext_vector_type(8))) short bf16x8;
typedef __attribute__((ext_vector_type(4))) float f32x4;

__device__ inline int pack_bf16(float a, float b) {
  union { __hip_bfloat16 h; unsigned short u; } ua, ub;
  ua.h = __float2bfloat16(a);
  ub.h = __float2bfloat16(b);
  return (int)(((unsigned)ub.u << 16) | (unsigned)ua.u);
}

// async global->LDS 16B: global ptr is PER-LANE; LDS dest must equal
// wave-uniform base + lane*16. Callers pass per-lane g AND l = base+lane*16.
__device__ inline void gl_lds16(const __hip_bfloat16* g, __hip_bfloat16* l) {
  __builtin_amdgcn_global_load_lds(
      (const __attribute__((address_space(1))) unsigned int*)g,
      (__attribute__((address_space(3))) unsigned int*)l, 16, 0, 0);
}

// ---------------------------------------------------------------------------
// prep1: fused {fp32->bf16 x conversion} + {3x weight transpose to bf16}.
// blocks [0,2048): cvt (8 elems/thread). blocks [2048,2816): cvtT (z = id>>8).
// ---------------------------------------------------------------------------
__global__ __launch_bounds__(256) void prep1_kernel(const float* __restrict__ x,
                                                    const float* __restrict__ W_la,
                                                    const float* __restrict__ W_v,
                                                    const float* __restrict__ W_proj,
                                                    __hip_bfloat16* __restrict__ x16,
                                                    __hip_bfloat16* __restrict__ Wcat,
                                                    __hip_bfloat16* __restrict__ WprojT) {
  __shared__ __hip_bfloat16 tile[64][66];
  const int bid = (int)blockIdx.x;
  if (bid < 2048) {
    const int i = (bid * 256 + (int)threadIdx.x) * 8;
    const float4 a = *reinterpret_cast<const float4*>(x + i);
    const float4 b = *reinterpret_cast<const float4*>(x + i + 4);
    union { int s[4]; int4 v; } u;
    u.s[0] = pack_bf16(a.x, a.y);
    u.s[1] = pack_bf16(a.z, a.w);
    u.s[2] = pack_bf16(b.x, b.y);
    u.s[3] = pack_bf16(b.z, b.w);
    *reinterpret_cast<int4*>(x16 + i) = u.v;
    return;
  }
  const int id = bid - 2048;        // 0..767
  const int z = id >> 8;            // 0..2
  const int rem = id & 255;
  const int bx = rem & 15, by = rem >> 4;
  const float* W = (z == 0) ? W_la : (z == 1) ? W_v : W_proj;
  __hip_bfloat16* WT = (z == 2) ? WprojT : Wcat + (size_t)z * C_ * C_;
  const int w = threadIdx.x >> 6, l = threadIdx.x & 63;
  const int n0 = bx * 64, k0 = by * 64;
#pragma unroll
  for (int r = 0; r < 16; ++r) {
    const int k = k0 + w * 16 + r;
    tile[w * 16 + r][l] = __float2bfloat16(W[(size_t)k * C_ + n0 + l]);
  }
  __syncthreads();
#pragma unroll
  for (int r = 0; r < 16; ++r) {
    const int nn = w * 16 + r;
    WT[(size_t)(n0 + nn) * C_ + k0 + l] = tile[l][nn];
  }
}

// ---------------------------------------------------------------------------
// Combined input GEMM: [xl | xv] = x16(4096x1024) @ Wcat(2048x1024)^T.
// 2-phase double-buffered pipeline, counted vmcnt, raw s_barrier.
// ---------------------------------------------------------------------------
__global__ __launch_bounds__(256) void gemm_in_kernel(const __hip_bfloat16* __restrict__ A,
                                                      const __hip_bfloat16* __restrict__ BT,
                                                      float* __restrict__ C0,
                                                      float* __restrict__ C1) {
  __shared__ __hip_bfloat16 As[2 * 128 * 32];
  __shared__ __hip_bfloat16 Bs[2 * 128 * 32];
  const int tid = threadIdx.x;
  const int m0 = blockIdx.y * 128, n0 = blockIdx.x * 128;
  const int w = tid >> 6, l = tid & 63;
  const int n = l & 15, kg = l >> 4;
  const int m0w = (w & 1) * 64, n0w = (w >> 1) * 64;

  const int r0 = tid >> 2, o0 = (tid & 3) * 8;
  const __hip_bfloat16* ag0 = A + (size_t)(m0 + r0) * C_ + o0;
  const __hip_bfloat16* ag1 = A + (size_t)(m0 + 64 + r0) * C_ + o0;
  const __hip_bfloat16* bg0 = BT + (size_t)(n0 + r0) * C_ + o0;
  const __hip_bfloat16* bg1 = BT + (size_t)(n0 + 64 + r0) * C_ + o0;

  f32x4 acc[4][4];
#pragma unroll
  for (int i = 0; i < 4; ++i)
#pragma unroll
    for (int j = 0; j < 4; ++j) acc[i][j] = f32x4{0.f, 0.f, 0.f, 0.f};

  auto stage = [&](int kk, int buf) {
    __hip_bfloat16* a = As + buf * 4096;
    __hip_bfloat16* b = Bs + buf * 4096;
    gl_lds16(ag0 + kk, a + tid * 8);
    gl_lds16(ag1 + kk, a + 2048 + tid * 8);
    gl_lds16(bg0 + kk, b + tid * 8);
    gl_lds16(bg1 + kk, b + 2048 + tid * 8);
  };

  stage(0, 0);
  int cur = 0;
  for (int k0 = 0; k0 < C_; k0 += 32) {
    asm volatile("" ::: "memory");
    __builtin_amdgcn_s_barrier();   // buf[cur^1] readers (iter-1) done
    asm volatile("" ::: "memory");
    if (k0 + 32 < C_) {
      stage(k0 + 32, cur ^ 1);
      asm volatile("s_waitcnt vmcnt(4)" ::: "memory");  // older 4 (this tile) landed
    } else {
      asm volatile("s_waitcnt vmcnt(0)" ::: "memory");
    }
    __builtin_amdgcn_s_barrier();   // all waves' tile-k0 DMAs landed
    asm volatile("" ::: "memory");

    const __hip_bfloat16* Ab = As + cur * 4096;
    const __hip_bfloat16* Bb = Bs + cur * 4096;
    bf16x8 af[4], bf[4];
#pragma unroll
    for (int ms = 0; ms < 4; ++ms)
      af[ms] = *reinterpret_cast<const bf16x8*>(Ab + (m0w + ms * 16 + n) * 32 + kg * 8);
#pragma unroll
    for (int ns = 0; ns < 4; ++ns)
      bf[ns] = *reinterpret_cast<const bf16x8*>(Bb + (n0w + ns * 16 + n) * 32 + kg * 8);
#pragma unroll
    for (int ms = 0; ms < 4; ++ms)
#pragma unroll
      for (int ns = 0; ns < 4; ++ns)
        acc[ms][ns] = __builtin_amdgcn_mfma_f32_16x16x32_bf16(af[ms], bf[ns], acc[ms][ns], 0, 0, 0);
    cur ^= 1;
  }

  float* Cb = (n0 < C_) ? C0 : C1;
  const int nc = (n0 < C_) ? n0 : n0 - C_;
#pragma unroll
  for (int ms = 0; ms < 4; ++ms) {
#pragma unroll
    for (int r = 0; r < 4; ++r) {
      const int row = m0 + m0w + ms * 16 + kg * 4 + r;
      float* cp = Cb + (size_t)row * C_ + nc + n0w + n;
#pragma unroll
      for (int ns = 0; ns < 4; ++ns) cp[ns * 16] = acc[ms][ns][r];
    }
  }
}

// ---------------------------------------------------------------------------
// Projection GEMM: out = y16(4096x1024) @ WprojT(1024x1024)^T, fp32 out.
// ---------------------------------------------------------------------------
__global__ __launch_bounds__(256) void gemm_proj_kernel(const __hip_bfloat16* __restrict__ A,
                                                        const __hip_bfloat16* __restrict__ BT,
                                                        float* __restrict__ Cout) {
  __shared__ __hip_bfloat16 As[2 * 64 * 32];
  __shared__ __hip_bfloat16 Bs[2 * 128 * 32];
  const int tid = threadIdx.x;
  const int m0 = blockIdx.y * 64, n0 = blockIdx.x * 128;
  const int w = tid >> 6, l = tid & 63;
  const int n = l & 15, kg = l >> 4;

  const int r0 = tid >> 2, o0 = (tid & 3) * 8;
  const __hip_bfloat16* ag = A + (size_t)(m0 + r0) * C_ + o0;
  const __hip_bfloat16* bg0 = BT + (size_t)(n0 + r0) * C_ + o0;
  const __hip_bfloat16* bg1 = BT + (size_t)(n0 + 64 + r0) * C_ + o0;

  f32x4 acc[4][2];
#pragma unroll
  for (int i = 0; i < 4; ++i)
#pragma unroll
    for (int j = 0; j < 2; ++j) acc[i][j] = f32x4{0.f, 0.f, 0.f, 0.f};

  auto stage = [&](int kk, int buf) {
    __hip_bfloat16* a = As + buf * 2048;
    __hip_bfloat16* b = Bs + buf * 4096;
    gl_lds16(ag + kk, a + tid * 8);
    gl_lds16(bg0 + kk, b + tid * 8);
    gl_lds16(bg1 + kk, b + 2048 + tid * 8);
  };

  stage(0, 0);
  int cur = 0;
  for (int k0 = 0; k0 < C_; k0 += 32) {
    asm volatile("" ::: "memory");
    __builtin_amdgcn_s_barrier();
    asm volatile("" ::: "memory");
    if (k0 + 32 < C_) {
      stage(k0 + 32, cur ^ 1);
      asm volatile("s_waitcnt vmcnt(3)" ::: "memory");
    } else {
      asm volatile("s_waitcnt vmcnt(0)" ::: "memory");
    }
    __builtin_amdgcn_s_barrier();
    asm volatile("" ::: "memory");

    const __hip_bfloat16* Ab = As + cur * 2048;
    const __hip_bfloat16* Bb = Bs + cur * 4096;
    bf16x8 af[4], bf[2];
#pragma unroll
    for (int ms = 0; ms < 4; ++ms)
      af[ms] = *reinterpret_cast<const bf16x8*>(Ab + (ms * 16 + n) * 32 + kg * 8);
#pragma unroll
    for (int ns = 0; ns < 2; ++ns)
      bf[ns] = *reinterpret_cast<const bf16x8*>(Bb + (w * 32 + ns * 16 + n) * 32 + kg * 8);
#pragma unroll
    for (int ms = 0; ms < 4; ++ms)
#pragma unroll
      for (int ns = 0; ns < 2; ++ns)
        acc[ms][ns] = __builtin_amdgcn_mfma_f32_16x16x32_bf16(af[ms], bf[ns], acc[ms][ns], 0, 0, 0);
    cur ^= 1;
  }

#pragma unroll
  for (int ms = 0; ms < 4; ++ms) {
#pragma unroll
    for (int r = 0; r < 4; ++r) {
      const int row = m0 + ms * 16 + kg * 4 + r;
      float* cp = Cout + (size_t)row * C_ + n0 + w * 32 + n;
#pragma unroll
      for (int ns = 0; ns < 2; ++ns) cp[ns * 16] = acc[ms][ns][r];
    }
  }
}

// ---------------------------------------------------------------------------
// prep2: fused {vprep, LDS-STAGED} (blocks [0,1024)) + {EMA, 4-wave scan}
// (blocks [1024,1536)). R9's EMA-first + reg-double-stage REVERTED (regressed
// +10us; VMEM burst). New: vprep stages its 65-row xv slice into LDS via ~5
// batched independent float4 loads/thread (was 32 latency-serialized 256B
// loads interleaved with dependent shfl chains -> ~1 TB/s effective). The
// compute/reduce loop then runs entirely from LDS (stride-64 rows: 2-way
// bank aliasing = free).
// ---------------------------------------------------------------------------
__global__ __launch_bounds__(256) void prep2_kernel(const float* __restrict__ xv,
                                                    const float* __restrict__ xl,
                                                    __hip_bfloat16* __restrict__ vt,
                                                    __hip_bfloat16* __restrict__ kb16,
                                                    const float* __restrict__ value_beta,
                                                    const float* __restrict__ v_coef,
                                                    const float* __restrict__ la_coef,
                                                    const float* __restrict__ kernel_beta) {
  __shared__ float4 smem4[2048];   // 32 KB, shared by both paths
  __shared__ float carrW[4][64];   // warmup carries  (1 KB)
  __shared__ float carrS[4][64];   // own-chunk carries (1 KB)
  const int bid = (int)blockIdx.x;
  if (bid < 1024) {
    // ---- vprep: LDS-staged ----
    float* cache = reinterpret_cast<float*>(smem4);            // 65 x 64 f32 = 16640 B
    __hip_bfloat16 (*tile)[66] =
        reinterpret_cast<__hip_bfloat16(*)[66]>(reinterpret_cast<char*>(smem4) + 16640);
    const int tc = bid % NT_;
    const int bh = bid / NT_;
    const int h = bh % NH_, b = bh / NH_;
    const int t0 = tc * 64;
    const int tid = threadIdx.x;
    const int w = tid >> 6, l = tid & 63;

    const float c = v_coef[h];
    const float vb = expf(value_beta[h] * 10.0f);

    // batched staging: rows t0..t0+64 (65 rows x 16 float4), all independent
    const float4* xv4 = reinterpret_cast<const float4*>(xv);
    float4* cache4 = reinterpret_cast<float4*>(cache);
#pragma unroll
    for (int i = 0; i < 5; ++i) {
      const int idx = tid + i * 256;
      if (idx < 65 * 16) {
        const int row = idx >> 4, c4 = idx & 15;
        const int t = t0 + row;
        float4 v = {0.f, 0.f, 0.f, 0.f};
        if (t < T_) v = xv4[((size_t)b * T_ + t) * (C_ / 4) + h * (HS_ / 4) + c4];
        cache4[row * 16 + c4] = v;
      }
    }
    __syncthreads();

    for (int r = 0; r < 16; ++r) {
      const int tl = w * 16 + r;
      const float cu = cache[tl * HS_ + l];
      const float nxt = cache[(tl + 1) * HS_ + l];
      float val = nxt * (1.0f - c) + cu * c;
      float ssum = val * val;
#pragma unroll
      for (int m = 32; m; m >>= 1) ssum += __shfl_xor(ssum, m);
      tile[tl][l] = __float2bfloat16(val * (vb / sqrtf(ssum)));
    }
    __syncthreads();
    __hip_bfloat16* vtb = vt + (size_t)(bh * NT_ + tc) * TEL_;
    const int kk = l >> 3, j = l & 7;  // l = key
    for (int rr = 0; rr < 16; ++rr) {
      const int hs = w * 16 + rr;
      vtb[(kk * 64 + hs) * 8 + j] = tile[l][hs];
    }
    return;
  }
  // ---- EMA: 4-wave chunked scan + norm + kb16 slot emit (R8 form) ----
  {
    float* buf = reinterpret_cast<float*>(smem4);  // 128 x 64 fp32 = 32 KB
    const int idx = bid - 1024;
    const int c = idx % SCN_;
    const int bh = idx / SCN_;
    const int b = bh / NH_, h = bh % NH_;
    const int tid = threadIdx.x;
    const int w = tid >> 6, l = tid & 63;

    const float alpha = la_coef[h];
    const float onema = 1.0f - alpha;
    const float a32 = __powf(alpha, 32.0f);
    const float kbs = expf(fminf(kernel_beta[h] * 10.0f, 5.0f));
    const float4* src4 = reinterpret_cast<const float4*>(xl + (size_t)b * T_ * C_ + h * HS_);
    float4* buf4 = reinterpret_cast<float4*>(buf);

    auto stageChunk = [&](int t0s) {
#pragma unroll
      for (int i = 0; i < 8; ++i) {
        const int ix = tid + i * 256;
        const int tt = ix >> 4, d4 = ix & 15;
        buf4[tt * 16 + d4] = src4[(size_t)(t0s + tt) * (C_ / 4) + d4];
      }
    };
    // local zero-init scan of this wave's 32 rows; returns carry (lane=dim)
    auto localCarry = [&]() -> float {
      float A = 0.0f;
      const float* bp = buf + (w * 32) * HS_ + l;
#pragma unroll 8
      for (int tt = 0; tt < 32; ++tt) A = alpha * A + onema * bp[tt * HS_];
      return A;
    };

    float W = 0.0f;  // combined carry of previous chunk (truncated history)
    if (c > 0) {
      stageChunk((c - 1) * SCL_);
      __syncthreads();
      carrW[w][l] = localCarry();
      __syncthreads();
      W = ((carrW[0][l] * a32 + carrW[1][l]) * a32 + carrW[2][l]) * a32 + carrW[3][l];
    }
    const int t0 = c * SCL_;
    __syncthreads();          // warmup buf reads done (no-op cost when c==0)
    stageChunk(t0);
    __syncthreads();
    carrS[w][l] = localCarry();
    __syncthreads();
    // prefix state for this wave: P_w = carry of all rows before row 32w
    float P = W;
#pragma unroll
    for (int j2 = 0; j2 < 3; ++j2)
      if (j2 < w) P = carrS[j2][l] + a32 * P;  // wave-uniform branch
    // pass 2: re-scan with init P -> exact value; fuse norm + emit
    __hip_bfloat16* kt = kb16 + (size_t)bh * NT_ * TEL_;
    const int g = l >> 3, j = l & 7;
    const float* bp = buf + (w * 32) * HS_ + l;
    float A = P;
    for (int rr = 0; rr < 32; ++rr) {
      A = alpha * A + onema * bp[rr * HS_];
      float ss = A * A;
#pragma unroll
      for (int m = 32; m; m >>= 1) ss += __shfl_xor(ss, m);
      const int t = t0 + w * 32 + rr;
      const int tile = t >> 6, key = t & 63;
      kt[(size_t)tile * TEL_ + (g * 64 + key) * 8 + j] = __float2bfloat16(A * (kbs / sqrtf(ss)));
    }
  }
}

// ---------------------------------------------------------------------------
// MFMA flash attention, V-DIRECT + 2-TILE PAIRED iterations (R5 config:
// best measured). Ks = 2 buf x 2 tiles (32 KB) + Ps 8 KB = 40960 B ->
// 4 blocks/CU. Per pair: 2 barriers serve TWO 64-key tiles; tile B sync-free.
// vmcnt: outstanding at wait = oldK(4) + vfA(8) + newK(c) -> vmcnt(8+c).
// ---------------------------------------------------------------------------
__global__ __launch_bounds__(256, 4) void attn_mfma_kernel(
    const __hip_bfloat16* __restrict__ kb,   // (BH, NT, g, key, 8) slot tiles
    const __hip_bfloat16* __restrict__ vt,   // (BH, NT, kk, hs, 8) slot tiles
    __hip_bfloat16* __restrict__ y) {        // (B, T, C) bf16
  __shared__ __hip_bfloat16 Ks[2][2 * TEL_]; // 32 KB: [buf][tile0|tile1]
  __shared__ __hip_bfloat16 Ps[4][16 * 64];  // 8 KB, XOR-swizzled granules

  const int id = (int)blockIdx.x;
  const int xcd = id & 7;
  const int s = id >> 3;                 // 0..127
  const int bh = xcd + 8 * (s & 3);      // 32 bh, grouped 4 per XCD
  const int v = s >> 2;                  // 0..31
  const int qt = (v < 16) ? (31 - v) : (v - 16);  // balanced bijection
  const int b = bh / NH_, h = bh % NH_;
  const int q0 = qt * 64;
  const int w = threadIdx.x >> 6;
  const int l = threadIdx.x & 63;
  const int n = l & 15;
  const int kg = l >> 4;
  const int qq = w * 16 + n;             // within-tile query index
  const int query = q0 + qq;
  const int lo = l * 8;                  // per-lane 16B offset (elements)
  const int tb = bh * NT_;
  const int so = w * 1024 + lo;          // per-wave stage offset (elements)

  // Q B-fragments from global slot tile (once)
  bf16x8 qf0, qf1;
  {
    const __hip_bfloat16* qtile = kb + (size_t)(tb + qt) * TEL_;
    qf0 = *reinterpret_cast<const bf16x8*>(qtile + (kg * 64 + qq) * 8);
    qf1 = *reinterpret_cast<const bf16x8*>(qtile + ((kg + 4) * 64 + qq) * 8);
  }
  // per-lane V fragment base: fragment (ks,mo) at vbase + ks*2048 + mo*128
  const __hip_bfloat16* vbase = vt + (size_t)tb * TEL_ + (kg * 64 + n) * 8;

  f32x4 accO[4];
#pragma unroll
  for (int i = 0; i < 4; ++i) accO[i] = f32x4{0.f, 0.f, 0.f, 0.f};
  float l_acc = 0.0f;

  __hip_bfloat16* Pw = Ps[w];
  int* Pwi = reinterpret_cast<int*>(Pw);

  auto stage2 = [&](int j0, int buf) {   // 4 DMAs: tiles j0, j0+1
    const size_t tg = (size_t)(tb + j0) * TEL_;
    __hip_bfloat16* Kb = &Ks[buf][0];
    gl_lds16(kb + tg + so, Kb + so);
    gl_lds16(kb + tg + so + 512, Kb + so + 512);
    gl_lds16(kb + tg + TEL_ + so, Kb + TEL_ + so);
    gl_lds16(kb + tg + TEL_ + so + 512, Kb + TEL_ + so + 512);
  };
  auto stage1 = [&](int j0, int buf) {   // 2 DMAs: tile j0 into half 0
    const size_t tg = (size_t)(tb + j0) * TEL_;
    __hip_bfloat16* Kb = &Ks[buf][0];
    gl_lds16(kb + tg + so, Kb + so);
    gl_lds16(kb + tg + so + 512, Kb + so + 512);
  };
  auto loadV = [&](int jt, bf16x8 (&vf)[2][4]) {
    const __hip_bfloat16* vp = vbase + (size_t)jt * TEL_;
#pragma unroll
    for (int ks = 0; ks < 2; ++ks)
#pragma unroll
      for (int mo = 0; mo < 4; ++mo)
        vf[ks][mo] = *reinterpret_cast<const bf16x8*>(vp + ks * 2048 + mo * 128);
  };
  auto computeS = [&](const __hip_bfloat16* Kc, f32x4 (&accS)[4]) {
    __builtin_amdgcn_s_setprio(1);
#pragma unroll
    for (int ms = 0; ms < 4; ++ms) {
      bf16x8 a0 = *reinterpret_cast<const bf16x8*>(Kc + (kg * 64 + ms * 16 + n) * 8);
      bf16x8 a1 = *reinterpret_cast<const bf16x8*>(Kc + ((kg + 4) * 64 + ms * 16 + n) * 8);
      f32x4 z{0.f, 0.f, 0.f, 0.f};
      z = __builtin_amdgcn_mfma_f32_16x16x32_bf16(a0, qf0, z, 0, 0, 0);
      accS[ms] = __builtin_amdgcn_mfma_f32_16x16x32_bf16(a1, qf1, z, 0, 0, 0);
    }
    __builtin_amdgcn_s_setprio(0);
  };
  auto softmaxStore = [&](const f32x4 (&accS)[4], bool diag) {
    if (!diag) {
#pragma unroll
      for (int ms = 0; ms < 4; ++ms) {
        const float p0 = __expf(accS[ms][0]), p1 = __expf(accS[ms][1]);
        const float p2 = __expf(accS[ms][2]), p3 = __expf(accS[ms][3]);
        l_acc += p0 + p1 + p2 + p3;
        const int po = n * 32 + (((ms * 4 + kg) ^ n) << 1);
        int2 pw;
        pw.x = pack_bf16(p0, p1);
        pw.y = pack_bf16(p2, p3);
        *reinterpret_cast<int2*>(&Pwi[po]) = pw;
      }
    } else {
#pragma unroll
      for (int ms = 0; ms < 4; ++ms) {
        const int kbase = ms * 16 + kg * 4;
        float p[4];
#pragma unroll
        for (int r = 0; r < 4; ++r) {
          const float e = __expf(accS[ms][r]);
          p[r] = (kbase + r < qq) ? e : 0.0f;
          l_acc += p[r];
        }
        const int po = n * 32 + (((ms * 4 + kg) ^ n) << 1);
        int2 pw;
        pw.x = pack_bf16(p[0], p[1]);
        pw.y = pack_bf16(p[2], p[3]);
        *reinterpret_cast<int2*>(&Pwi[po]) = pw;
      }
    }
  };
  auto pv = [&](const bf16x8 (&vf)[2][4]) {
    __builtin_amdgcn_s_setprio(1);
#pragma unroll
    for (int ks = 0; ks < 2; ++ks) {
      union { ushort4 u[2]; bf16x8 vv; } pr;
      const int ga = (ks * 8 + kg * 2) ^ n;      // granule of keys kg*8+0..3
      const __hip_bfloat16* pp = Pw + n * 64;
      pr.u[0] = *reinterpret_cast<const ushort4*>(pp + ga * 4);
      pr.u[1] = *reinterpret_cast<const ushort4*>(pp + (ga ^ 1) * 4);
#pragma unroll
      for (int mo = 0; mo < 4; ++mo)
        accO[mo] = __builtin_amdgcn_mfma_f32_16x16x32_bf16(vf[ks][mo], pr.vv, accO[mo], 0, 0, 0);
    }
    __builtin_amdgcn_s_setprio(0);
  };

  // prologue: stage first pair (or single) into buf 0
  if (qt >= 1) stage2(0, 0); else stage1(0, 0);

  int cur = 0;
  int jp = 0;
  for (; jp + 1 <= qt; jp += 2) {
    // barrier #1: all waves done reading Ks[cur^1]
    asm volatile("" ::: "memory");
    __builtin_amdgcn_s_barrier();
    asm volatile("" ::: "memory");

    bf16x8 vfA[2][4];
    loadV(jp, vfA);                     // 8 V loads (oldest after oldK)
    asm volatile("" ::: "memory");      // pin V issue before K-DMA

    const int nx = jp + 2;
    if (nx + 1 <= qt) {
      stage2(nx, cur ^ 1);
      asm volatile("s_waitcnt vmcnt(12)" ::: "memory");  // drain oldK(4)
    } else if (nx <= qt) {
      stage1(nx, cur ^ 1);
      asm volatile("s_waitcnt vmcnt(10)" ::: "memory");
    } else {
      asm volatile("s_waitcnt vmcnt(8)" ::: "memory");
    }
    // barrier #2: every wave's pair-K DMAs have landed
    __builtin_amdgcn_s_barrier();
    asm volatile("" ::: "memory");

    // ---- tile A (index jp, never diagonal in pair loop) ----
    f32x4 accS[4];
    computeS(&Ks[cur][0], accS);
    softmaxStore(accS, false);
    pv(vfA);

    asm volatile("" ::: "memory");  // tile A P-reads before tile B P-writes

    // ---- tile B (index jp+1, diag iff == qt); sync-free ----
    bf16x8 vfB[2][4];
    loadV(jp + 1, vfB);             // hidden under S(B)+softmax(B)
    computeS(&Ks[cur][TEL_], accS);
    softmaxStore(accS, jp + 1 == qt);
    pv(vfB);

    cur ^= 1;
  }
  if (jp <= qt) {  // peeled single (diagonal) tile
    asm volatile("" ::: "memory");
    __builtin_amdgcn_s_barrier();
    asm volatile("" ::: "memory");
    bf16x8 vfA[2][4];
    loadV(jp, vfA);
    asm volatile("s_waitcnt vmcnt(8)" ::: "memory");  // drain the 2 oldK
    __builtin_amdgcn_s_barrier();
    asm volatile("" ::: "memory");
    f32x4 accS[4];
    computeS(&Ks[cur][0], accS);
    softmaxStore(accS, true);
    pv(vfA);
  }

  // ---- deferred row reduction + epilogue ----
  l_acc += __shfl_xor(l_acc, 16);
  l_acc += __shfl_xor(l_acc, 32);
  const float inv = (query == 0) ? 0.0f : 1.0f / l_acc;
  __hip_bfloat16* yb = y + ((size_t)b * T_ + query) * C_ + h * HS_;
#pragma unroll
  for (int mo = 0; mo < 4; ++mo) {
    int2 pkd;
    pkd.x = pack_bf16(accO[mo][0] * inv, accO[mo][1] * inv);
    pkd.y = pack_bf16(accO[mo][2] * inv, accO[mo][3] * inv);
    *reinterpret_cast<int2*>(yb + mo * 16 + kg * 4) = pkd;
  }
}

// ---------------------------------------------------------------------------
extern "C" void kernel_launch(void* const* d_in, const int* in_sizes, int n_in,
                              void* d_out, int out_size, void* d_ws, size_t ws_size,
                              hipStream_t stream) {
  const float* x           = (const float*)d_in[0];
  const float* W_la        = (const float*)d_in[1];
  const float* la_coef     = (const float*)d_in[2];
  const float* kernel_beta = (const float*)d_in[3];
  const float* value_beta  = (const float*)d_in[4];
  const float* W_v         = (const float*)d_in[5];
  const float* v_coef      = (const float*)d_in[6];
  const float* W_proj      = (const float*)d_in[7];
  float* out = (float*)d_out;

  char* wsb = (char*)d_ws;
  const size_t MB = 1024u * 1024u;
  __hip_bfloat16* x16    = (__hip_bfloat16*)(wsb);            // 8 MB
  __hip_bfloat16* Wcat   = (__hip_bfloat16*)(wsb + 8 * MB);   // 4 MB (W_laT | W_vT)
  __hip_bfloat16* WprojT = (__hip_bfloat16*)(wsb + 12 * MB);  // 2 MB
  float* xl              = (float*)(wsb + 16 * MB);           // 16 MB
  float* xv              = (float*)(wsb + 32 * MB);           // 16 MB
  __hip_bfloat16* kb16   = (__hip_bfloat16*)(wsb + 48 * MB);  // 8 MB
  __hip_bfloat16* vt16   = (__hip_bfloat16*)(wsb + 56 * MB);  // 8 MB
  __hip_bfloat16* y16    = (__hip_bfloat16*)(wsb + 64 * MB);  // 8 MB (xl still
                                                              //  live during prep2)
  (void)ws_size; (void)in_sizes; (void)n_in; (void)out_size;

  const int M = B_ * T_;

  prep1_kernel<<<dim3(2048 + 768), dim3(256), 0, stream>>>(x, W_la, W_v, W_proj, x16, Wcat, WprojT);
  gemm_in_kernel<<<dim3(2 * C_ / 128, M / 128), dim3(256), 0, stream>>>(x16, Wcat, xl, xv);
  prep2_kernel<<<dim3(1024 + 512), dim3(256), 0, stream>>>(xv, xl, vt16, kb16,
                                                           value_beta, v_coef, la_coef, kernel_beta);
  attn_mfma_kernel<<<dim3(8 * 128), dim3(256), 0, stream>>>(kb16, vt16, y16);
  gemm_proj_kernel<<<dim3(C_ / 128, M / 64), dim3(256), 0, stream>>>(y16, WprojT, out);
}

// Round 11
// 186.867 us; speedup vs baseline: 1.0852x; 1.0160x over previous
//
#include <hip/hip_runtime.h>
#include <hip/hip_bf16.h>

#define B_  2
#define T_  2048
#define NH_ 16
#define HS_ 64
#define C_  1024
#define SCL_ 128              // EMA chunk length
#define SCN_ (T_ / SCL_)      // 16 chunks
#define NT_  (T_ / 64)        // 32 key/query tiles
#define TEL_ 4096             // elements per 64x64 tile

typedef __attribute__((ext_vector_type(8))) short bf16x8;
typedef __attribute__((ext_vector_type(4))) float f32x4;

__device__ inline int pack_bf16(float a, float b) {
  union { __hip_bfloat16 h; unsigned short u; } ua, ub;
  ua.h = __float2bfloat16(a);
  ub.h = __float2bfloat16(b);
  return (int)(((unsigned)ub.u << 16) | (unsigned)ua.u);
}

// async global->LDS 16B: global ptr is PER-LANE; LDS dest must equal
// wave-uniform base + lane*16. Callers pass per-lane g AND l = base+lane*16.
__device__ inline void gl_lds16(const __hip_bfloat16* g, __hip_bfloat16* l) {
  __builtin_amdgcn_global_load_lds(
      (const __attribute__((address_space(1))) unsigned int*)g,
      (__attribute__((address_space(3))) unsigned int*)l, 16, 0, 0);
}

// ---------------------------------------------------------------------------
// prep1: fused {fp32->bf16 x conversion} + {3x weight transpose to bf16}.
// blocks [0,2048): cvt (8 elems/thread). blocks [2048,2816): cvtT (z = id>>8).
// ---------------------------------------------------------------------------
__global__ __launch_bounds__(256) void prep1_kernel(const float* __restrict__ x,
                                                    const float* __restrict__ W_la,
                                                    const float* __restrict__ W_v,
                                                    const float* __restrict__ W_proj,
                                                    __hip_bfloat16* __restrict__ x16,
                                                    __hip_bfloat16* __restrict__ Wcat,
                                                    __hip_bfloat16* __restrict__ WprojT) {
  __shared__ __hip_bfloat16 tile[64][66];
  const int bid = (int)blockIdx.x;
  if (bid < 2048) {
    const int i = (bid * 256 + (int)threadIdx.x) * 8;
    const float4 a = *reinterpret_cast<const float4*>(x + i);
    const float4 b = *reinterpret_cast<const float4*>(x + i + 4);
    union { int s[4]; int4 v; } u;
    u.s[0] = pack_bf16(a.x, a.y);
    u.s[1] = pack_bf16(a.z, a.w);
    u.s[2] = pack_bf16(b.x, b.y);
    u.s[3] = pack_bf16(b.z, b.w);
    *reinterpret_cast<int4*>(x16 + i) = u.v;
    return;
  }
  const int id = bid - 2048;        // 0..767
  const int z = id >> 8;            // 0..2
  const int rem = id & 255;
  const int bx = rem & 15, by = rem >> 4;
  const float* W = (z == 0) ? W_la : (z == 1) ? W_v : W_proj;
  __hip_bfloat16* WT = (z == 2) ? WprojT : Wcat + (size_t)z * C_ * C_;
  const int w = threadIdx.x >> 6, l = threadIdx.x & 63;
  const int n0 = bx * 64, k0 = by * 64;
#pragma unroll
  for (int r = 0; r < 16; ++r) {
    const int k = k0 + w * 16 + r;
    tile[w * 16 + r][l] = __float2bfloat16(W[(size_t)k * C_ + n0 + l]);
  }
  __syncthreads();
#pragma unroll
  for (int r = 0; r < 16; ++r) {
    const int nn = w * 16 + r;
    WT[(size_t)(n0 + nn) * C_ + k0 + l] = tile[l][nn];
  }
}

// ---------------------------------------------------------------------------
// Combined input GEMM: [xl | xv] = x16(4096x1024) @ Wcat(2048x1024)^T.
// 2-phase double-buffered pipeline, counted vmcnt, raw s_barrier.
// ---------------------------------------------------------------------------
__global__ __launch_bounds__(256) void gemm_in_kernel(const __hip_bfloat16* __restrict__ A,
                                                      const __hip_bfloat16* __restrict__ BT,
                                                      float* __restrict__ C0,
                                                      float* __restrict__ C1) {
  __shared__ __hip_bfloat16 As[2 * 128 * 32];
  __shared__ __hip_bfloat16 Bs[2 * 128 * 32];
  const int tid = threadIdx.x;
  const int m0 = blockIdx.y * 128, n0 = blockIdx.x * 128;
  const int w = tid >> 6, l = tid & 63;
  const int n = l & 15, kg = l >> 4;
  const int m0w = (w & 1) * 64, n0w = (w >> 1) * 64;

  const int r0 = tid >> 2, o0 = (tid & 3) * 8;
  const __hip_bfloat16* ag0 = A + (size_t)(m0 + r0) * C_ + o0;
  const __hip_bfloat16* ag1 = A + (size_t)(m0 + 64 + r0) * C_ + o0;
  const __hip_bfloat16* bg0 = BT + (size_t)(n0 + r0) * C_ + o0;
  const __hip_bfloat16* bg1 = BT + (size_t)(n0 + 64 + r0) * C_ + o0;

  f32x4 acc[4][4];
#pragma unroll
  for (int i = 0; i < 4; ++i)
#pragma unroll
    for (int j = 0; j < 4; ++j) acc[i][j] = f32x4{0.f, 0.f, 0.f, 0.f};

  auto stage = [&](int kk, int buf) {
    __hip_bfloat16* a = As + buf * 4096;
    __hip_bfloat16* b = Bs + buf * 4096;
    gl_lds16(ag0 + kk, a + tid * 8);
    gl_lds16(ag1 + kk, a + 2048 + tid * 8);
    gl_lds16(bg0 + kk, b + tid * 8);
    gl_lds16(bg1 + kk, b + 2048 + tid * 8);
  };

  stage(0, 0);
  int cur = 0;
  for (int k0 = 0; k0 < C_; k0 += 32) {
    asm volatile("" ::: "memory");
    __builtin_amdgcn_s_barrier();   // buf[cur^1] readers (iter-1) done
    asm volatile("" ::: "memory");
    if (k0 + 32 < C_) {
      stage(k0 + 32, cur ^ 1);
      asm volatile("s_waitcnt vmcnt(4)" ::: "memory");  // older 4 (this tile) landed
    } else {
      asm volatile("s_waitcnt vmcnt(0)" ::: "memory");
    }
    __builtin_amdgcn_s_barrier();   // all waves' tile-k0 DMAs landed
    asm volatile("" ::: "memory");

    const __hip_bfloat16* Ab = As + cur * 4096;
    const __hip_bfloat16* Bb = Bs + cur * 4096;
    bf16x8 af[4], bf[4];
#pragma unroll
    for (int ms = 0; ms < 4; ++ms)
      af[ms] = *reinterpret_cast<const bf16x8*>(Ab + (m0w + ms * 16 + n) * 32 + kg * 8);
#pragma unroll
    for (int ns = 0; ns < 4; ++ns)
      bf[ns] = *reinterpret_cast<const bf16x8*>(Bb + (n0w + ns * 16 + n) * 32 + kg * 8);
#pragma unroll
    for (int ms = 0; ms < 4; ++ms)
#pragma unroll
      for (int ns = 0; ns < 4; ++ns)
        acc[ms][ns] = __builtin_amdgcn_mfma_f32_16x16x32_bf16(af[ms], bf[ns], acc[ms][ns], 0, 0, 0);
    cur ^= 1;
  }

  float* Cb = (n0 < C_) ? C0 : C1;
  const int nc = (n0 < C_) ? n0 : n0 - C_;
#pragma unroll
  for (int ms = 0; ms < 4; ++ms) {
#pragma unroll
    for (int r = 0; r < 4; ++r) {
      const int row = m0 + m0w + ms * 16 + kg * 4 + r;
      float* cp = Cb + (size_t)row * C_ + nc + n0w + n;
#pragma unroll
      for (int ns = 0; ns < 4; ++ns) cp[ns * 16] = acc[ms][ns][r];
    }
  }
}

// ---------------------------------------------------------------------------
// Projection GEMM: out = y16(4096x1024) @ WprojT(1024x1024)^T, fp32 out.
// ---------------------------------------------------------------------------
__global__ __launch_bounds__(256) void gemm_proj_kernel(const __hip_bfloat16* __restrict__ A,
                                                        const __hip_bfloat16* __restrict__ BT,
                                                        float* __restrict__ Cout) {
  __shared__ __hip_bfloat16 As[2 * 64 * 32];
  __shared__ __hip_bfloat16 Bs[2 * 128 * 32];
  const int tid = threadIdx.x;
  const int m0 = blockIdx.y * 64, n0 = blockIdx.x * 128;
  const int w = tid >> 6, l = tid & 63;
  const int n = l & 15, kg = l >> 4;

  const int r0 = tid >> 2, o0 = (tid & 3) * 8;
  const __hip_bfloat16* ag = A + (size_t)(m0 + r0) * C_ + o0;
  const __hip_bfloat16* bg0 = BT + (size_t)(n0 + r0) * C_ + o0;
  const __hip_bfloat16* bg1 = BT + (size_t)(n0 + 64 + r0) * C_ + o0;

  f32x4 acc[4][2];
#pragma unroll
  for (int i = 0; i < 4; ++i)
#pragma unroll
    for (int j = 0; j < 2; ++j) acc[i][j] = f32x4{0.f, 0.f, 0.f, 0.f};

  auto stage = [&](int kk, int buf) {
    __hip_bfloat16* a = As + buf * 2048;
    __hip_bfloat16* b = Bs + buf * 4096;
    gl_lds16(ag + kk, a + tid * 8);
    gl_lds16(bg0 + kk, b + tid * 8);
    gl_lds16(bg1 + kk, b + 2048 + tid * 8);
  };

  stage(0, 0);
  int cur = 0;
  for (int k0 = 0; k0 < C_; k0 += 32) {
    asm volatile("" ::: "memory");
    __builtin_amdgcn_s_barrier();
    asm volatile("" ::: "memory");
    if (k0 + 32 < C_) {
      stage(k0 + 32, cur ^ 1);
      asm volatile("s_waitcnt vmcnt(3)" ::: "memory");
    } else {
      asm volatile("s_waitcnt vmcnt(0)" ::: "memory");
    }
    __builtin_amdgcn_s_barrier();
    asm volatile("" ::: "memory");

    const __hip_bfloat16* Ab = As + cur * 2048;
    const __hip_bfloat16* Bb = Bs + cur * 4096;
    bf16x8 af[4], bf[2];
#pragma unroll
    for (int ms = 0; ms < 4; ++ms)
      af[ms] = *reinterpret_cast<const bf16x8*>(Ab + (ms * 16 + n) * 32 + kg * 8);
#pragma unroll
    for (int ns = 0; ns < 2; ++ns)
      bf[ns] = *reinterpret_cast<const bf16x8*>(Bb + (w * 32 + ns * 16 + n) * 32 + kg * 8);
#pragma unroll
    for (int ms = 0; ms < 4; ++ms)
#pragma unroll
      for (int ns = 0; ns < 2; ++ns)
        acc[ms][ns] = __builtin_amdgcn_mfma_f32_16x16x32_bf16(af[ms], bf[ns], acc[ms][ns], 0, 0, 0);
    cur ^= 1;
  }

#pragma unroll
  for (int ms = 0; ms < 4; ++ms) {
#pragma unroll
    for (int r = 0; r < 4; ++r) {
      const int row = m0 + ms * 16 + kg * 4 + r;
      float* cp = Cout + (size_t)row * C_ + n0 + w * 32 + n;
#pragma unroll
      for (int ns = 0; ns < 2; ++ns) cp[ns * 16] = acc[ms][ns][r];
    }
  }
}

// ---------------------------------------------------------------------------
// prep2, LOW-LDS VARIANT (17.7 KB vs 34.8 KB -> 8 blocks/CU, was 4).
// Diagnosis (R7-R10): OccupancyPercent 29 with VALUBusy 24 -> resident waves
// are ~80% VALU-busy; prep2 is OCCUPANCY-capped by LDS, not latency-bound.
// vprep (blocks [0,1024)): stage 65 rows (16.6 KB), compute all 16 normalized
// values into REGISTERS, sync, then REUSE the cache region as the 64x66
// transpose tile (no separate 8.4 KB array).
// EMA (blocks [1024,1536)): 64-row HALF-chunk buffer (16 KB). 4-wave scan of
// 16-row strips, carries combined with a16/a64 Horner (identical fp32
// reassociation). Warmup 2 halves (carries only) + own 2 halves (scan +
// prefix + fused norm/emit). Truncated carry (alpha^128) unchanged.
// ---------------------------------------------------------------------------
__global__ __launch_bounds__(256) void prep2_kernel(const float* __restrict__ xv,
                                                    const float* __restrict__ xl,
                                                    __hip_bfloat16* __restrict__ vt,
                                                    __hip_bfloat16* __restrict__ kb16,
                                                    const float* __restrict__ value_beta,
                                                    const float* __restrict__ v_coef,
                                                    const float* __restrict__ la_coef,
                                                    const float* __restrict__ kernel_beta) {
  __shared__ float smemf[65 * 64];   // 16640 B (vprep cache / EMA 64-row buf)
  __shared__ float carrP[4][64];     // 1 KB strip carries
  const int bid = (int)blockIdx.x;
  const int tid = threadIdx.x;
  const int w = tid >> 6, l = tid & 63;

  if (bid < 1024) {
    // ---- vprep: LDS-staged, tile overlays cache after reg buffering ----
    float* cache = smemf;
    const int tc = bid % NT_;
    const int bh = bid / NT_;
    const int h = bh % NH_, b = bh / NH_;
    const int t0 = tc * 64;

    const float c = v_coef[h];
    const float vb = expf(value_beta[h] * 10.0f);

    const float4* xv4 = reinterpret_cast<const float4*>(xv);
    float4* cache4 = reinterpret_cast<float4*>(cache);
#pragma unroll
    for (int i = 0; i < 5; ++i) {
      const int idx = tid + i * 256;
      if (idx < 65 * 16) {
        const int row = idx >> 4, c4 = idx & 15;
        const int t = t0 + row;
        float4 v = {0.f, 0.f, 0.f, 0.f};
        if (t < T_) v = xv4[((size_t)b * T_ + t) * (C_ / 4) + h * (HS_ / 4) + c4];
        cache4[row * 16 + c4] = v;
      }
    }
    __syncthreads();

    // compute all 16 normalized bf16 values into registers
    unsigned short us[16];
#pragma unroll
    for (int r = 0; r < 16; ++r) {
      const int tl = w * 16 + r;
      const float cu = cache[tl * HS_ + l];
      const float nxt = cache[(tl + 1) * HS_ + l];
      float val = nxt * (1.0f - c) + cu * c;
      float ssum = val * val;
#pragma unroll
      for (int m = 32; m; m >>= 1) ssum += __shfl_xor(ssum, m);
      union { __hip_bfloat16 hh; unsigned short uu; } cvt;
      cvt.hh = __float2bfloat16(val * (vb / sqrtf(ssum)));
      us[r] = cvt.uu;
    }
    __syncthreads();  // ALL cache reads done -> safe to overlay tile

    __hip_bfloat16 (*tile)[66] = reinterpret_cast<__hip_bfloat16(*)[66]>(smemf);
#pragma unroll
    for (int r = 0; r < 16; ++r) {
      union { __hip_bfloat16 hh; unsigned short uu; } cvt;
      cvt.uu = us[r];
      tile[w * 16 + r][l] = cvt.hh;
    }
    __syncthreads();
    __hip_bfloat16* vtb = vt + (size_t)(bh * NT_ + tc) * TEL_;
    const int kk = l >> 3, j = l & 7;  // l = key
    for (int rr = 0; rr < 16; ++rr) {
      const int hs = w * 16 + rr;
      vtb[(kk * 64 + hs) * 8 + j] = tile[l][hs];
    }
    return;
  }
  // ---- EMA: half-chunk (64-row) scan, 16 KB buffer ----
  {
    float* buf = smemf;  // first 64*64 floats used
    const int idx = bid - 1024;
    const int c = idx % SCN_;
    const int bh = idx / SCN_;
    const int b = bh / NH_, h = bh % NH_;

    const float alpha = la_coef[h];
    const float onema = 1.0f - alpha;
    const float a16 = __powf(alpha, 16.0f);
    const float a32 = a16 * a16;
    const float a64 = a32 * a32;
    const float kbs = expf(fminf(kernel_beta[h] * 10.0f, 5.0f));
    const float4* src4 = reinterpret_cast<const float4*>(xl + (size_t)b * T_ * C_ + h * HS_);
    float4* buf4 = reinterpret_cast<float4*>(buf);

    auto stageHalf = [&](int t0s) {  // 64 rows from t0s
#pragma unroll
      for (int i = 0; i < 4; ++i) {
        const int ix = tid + i * 256;
        const int tt = ix >> 4, d4 = ix & 15;
        buf4[tt * 16 + d4] = src4[(size_t)(t0s + tt) * (C_ / 4) + d4];
      }
    };
    auto scan16 = [&]() -> float {   // zero-init scan of wave's 16-row strip
      float A = 0.0f;
      const float* bp = buf + (w * 16) * HS_ + l;
#pragma unroll 4
      for (int tt = 0; tt < 16; ++tt) A = alpha * A + onema * bp[tt * HS_];
      return A;
    };
    auto comb = [&]() -> float {     // combined carry of 64 rows (4 strips)
      return ((carrP[0][l] * a16 + carrP[1][l]) * a16 + carrP[2][l]) * a16 + carrP[3][l];
    };

    const int t0 = c * SCL_;
    float W = 0.0f;                  // state at chunk start (truncated hist)
    if (c > 0) {
      stageHalf(t0 - SCL_);
      __syncthreads();
      carrP[w][l] = scan16();
      __syncthreads();
      const float Cw0 = comb();
      stageHalf(t0 - SCL_ + 64);     // overwrite buf (carr reads done pre-sync? comb read
      __syncthreads();               //  happened before this sync; carr rewritten below)
      carrP[w][l] = scan16();
      __syncthreads();
      W = a64 * Cw0 + comb();
    }

    __hip_bfloat16* kt = kb16 + (size_t)bh * NT_ * TEL_;
    const int g = l >> 3, j = l & 7;

    float Shalf = W;                 // state entering current half
#pragma unroll
    for (int hf = 0; hf < 2; ++hf) {
      __syncthreads();               // prior buf reads done before restage
      stageHalf(t0 + hf * 64);
      __syncthreads();
      carrP[w][l] = scan16();
      __syncthreads();
      const float Snext = a64 * Shalf + comb();   // state entering next half
      float P = Shalf;
#pragma unroll
      for (int j2 = 0; j2 < 3; ++j2)
        if (j2 < w) P = carrP[j2][l] + a16 * P;   // wave-uniform branch
      // pass 2: re-scan strip with init P -> exact values; fused norm+emit
      const float* bp = buf + (w * 16) * HS_ + l;
      float A = P;
      for (int rr = 0; rr < 16; ++rr) {
        A = alpha * A + onema * bp[rr * HS_];
        float ss = A * A;
#pragma unroll
        for (int m = 32; m; m >>= 1) ss += __shfl_xor(ss, m);
        const int t = t0 + hf * 64 + w * 16 + rr;
        const int tile = t >> 6, key = t & 63;
        kt[(size_t)tile * TEL_ + (g * 64 + key) * 8 + j] = __float2bfloat16(A * (kbs / sqrtf(ss)));
      }
      Shalf = Snext;
    }
  }
}

// ---------------------------------------------------------------------------
// MFMA flash attention, V-DIRECT + 2-TILE PAIRED iterations (R5 config:
// best measured). Ks = 2 buf x 2 tiles (32 KB) + Ps 8 KB = 40960 B ->
// 4 blocks/CU. Per pair: 2 barriers serve TWO 64-key tiles; tile B sync-free.
// vmcnt: outstanding at wait = oldK(4) + vfA(8) + newK(c) -> vmcnt(8+c).
// ---------------------------------------------------------------------------
__global__ __launch_bounds__(256, 4) void attn_mfma_kernel(
    const __hip_bfloat16* __restrict__ kb,   // (BH, NT, g, key, 8) slot tiles
    const __hip_bfloat16* __restrict__ vt,   // (BH, NT, kk, hs, 8) slot tiles
    __hip_bfloat16* __restrict__ y) {        // (B, T, C) bf16
  __shared__ __hip_bfloat16 Ks[2][2 * TEL_]; // 32 KB: [buf][tile0|tile1]
  __shared__ __hip_bfloat16 Ps[4][16 * 64];  // 8 KB, XOR-swizzled granules

  const int id = (int)blockIdx.x;
  const int xcd = id & 7;
  const int s = id >> 3;                 // 0..127
  const int bh = xcd + 8 * (s & 3);      // 32 bh, grouped 4 per XCD
  const int v = s >> 2;                  // 0..31
  const int qt = (v < 16) ? (31 - v) : (v - 16);  // balanced bijection
  const int b = bh / NH_, h = bh % NH_;
  const int q0 = qt * 64;
  const int w = threadIdx.x >> 6;
  const int l = threadIdx.x & 63;
  const int n = l & 15;
  const int kg = l >> 4;
  const int qq = w * 16 + n;             // within-tile query index
  const int query = q0 + qq;
  const int lo = l * 8;                  // per-lane 16B offset (elements)
  const int tb = bh * NT_;
  const int so = w * 1024 + lo;          // per-wave stage offset (elements)

  // Q B-fragments from global slot tile (once)
  bf16x8 qf0, qf1;
  {
    const __hip_bfloat16* qtile = kb + (size_t)(tb + qt) * TEL_;
    qf0 = *reinterpret_cast<const bf16x8*>(qtile + (kg * 64 + qq) * 8);
    qf1 = *reinterpret_cast<const bf16x8*>(qtile + ((kg + 4) * 64 + qq) * 8);
  }
  // per-lane V fragment base: fragment (ks,mo) at vbase + ks*2048 + mo*128
  const __hip_bfloat16* vbase = vt + (size_t)tb * TEL_ + (kg * 64 + n) * 8;

  f32x4 accO[4];
#pragma unroll
  for (int i = 0; i < 4; ++i) accO[i] = f32x4{0.f, 0.f, 0.f, 0.f};
  float l_acc = 0.0f;

  __hip_bfloat16* Pw = Ps[w];
  int* Pwi = reinterpret_cast<int*>(Pw);

  auto stage2 = [&](int j0, int buf) {   // 4 DMAs: tiles j0, j0+1
    const size_t tg = (size_t)(tb + j0) * TEL_;
    __hip_bfloat16* Kb = &Ks[buf][0];
    gl_lds16(kb + tg + so, Kb + so);
    gl_lds16(kb + tg + so + 512, Kb + so + 512);
    gl_lds16(kb + tg + TEL_ + so, Kb + TEL_ + so);
    gl_lds16(kb + tg + TEL_ + so + 512, Kb + TEL_ + so + 512);
  };
  auto stage1 = [&](int j0, int buf) {   // 2 DMAs: tile j0 into half 0
    const size_t tg = (size_t)(tb + j0) * TEL_;
    __hip_bfloat16* Kb = &Ks[buf][0];
    gl_lds16(kb + tg + so, Kb + so);
    gl_lds16(kb + tg + so + 512, Kb + so + 512);
  };
  auto loadV = [&](int jt, bf16x8 (&vf)[2][4]) {
    const __hip_bfloat16* vp = vbase + (size_t)jt * TEL_;
#pragma unroll
    for (int ks = 0; ks < 2; ++ks)
#pragma unroll
      for (int mo = 0; mo < 4; ++mo)
        vf[ks][mo] = *reinterpret_cast<const bf16x8*>(vp + ks * 2048 + mo * 128);
  };
  auto computeS = [&](const __hip_bfloat16* Kc, f32x4 (&accS)[4]) {
    __builtin_amdgcn_s_setprio(1);
#pragma unroll
    for (int ms = 0; ms < 4; ++ms) {
      bf16x8 a0 = *reinterpret_cast<const bf16x8*>(Kc + (kg * 64 + ms * 16 + n) * 8);
      bf16x8 a1 = *reinterpret_cast<const bf16x8*>(Kc + ((kg + 4) * 64 + ms * 16 + n) * 8);
      f32x4 z{0.f, 0.f, 0.f, 0.f};
      z = __builtin_amdgcn_mfma_f32_16x16x32_bf16(a0, qf0, z, 0, 0, 0);
      accS[ms] = __builtin_amdgcn_mfma_f32_16x16x32_bf16(a1, qf1, z, 0, 0, 0);
    }
    __builtin_amdgcn_s_setprio(0);
  };
  auto softmaxStore = [&](const f32x4 (&accS)[4], bool diag) {
    if (!diag) {
#pragma unroll
      for (int ms = 0; ms < 4; ++ms) {
        const float p0 = __expf(accS[ms][0]), p1 = __expf(accS[ms][1]);
        const float p2 = __expf(accS[ms][2]), p3 = __expf(accS[ms][3]);
        l_acc += p0 + p1 + p2 + p3;
        const int po = n * 32 + (((ms * 4 + kg) ^ n) << 1);
        int2 pw;
        pw.x = pack_bf16(p0, p1);
        pw.y = pack_bf16(p2, p3);
        *reinterpret_cast<int2*>(&Pwi[po]) = pw;
      }
    } else {
#pragma unroll
      for (int ms = 0; ms < 4; ++ms) {
        const int kbase = ms * 16 + kg * 4;
        float p[4];
#pragma unroll
        for (int r = 0; r < 4; ++r) {
          const float e = __expf(accS[ms][r]);
          p[r] = (kbase + r < qq) ? e : 0.0f;
          l_acc += p[r];
        }
        const int po = n * 32 + (((ms * 4 + kg) ^ n) << 1);
        int2 pw;
        pw.x = pack_bf16(p[0], p[1]);
        pw.y = pack_bf16(p[2], p[3]);
        *reinterpret_cast<int2*>(&Pwi[po]) = pw;
      }
    }
  };
  auto pv = [&](const bf16x8 (&vf)[2][4]) {
    __builtin_amdgcn_s_setprio(1);
#pragma unroll
    for (int ks = 0; ks < 2; ++ks) {
      union { ushort4 u[2]; bf16x8 vv; } pr;
      const int ga = (ks * 8 + kg * 2) ^ n;      // granule of keys kg*8+0..3
      const __hip_bfloat16* pp = Pw + n * 64;
      pr.u[0] = *reinterpret_cast<const ushort4*>(pp + ga * 4);
      pr.u[1] = *reinterpret_cast<const ushort4*>(pp + (ga ^ 1) * 4);
#pragma unroll
      for (int mo = 0; mo < 4; ++mo)
        accO[mo] = __builtin_amdgcn_mfma_f32_16x16x32_bf16(vf[ks][mo], pr.vv, accO[mo], 0, 0, 0);
    }
    __builtin_amdgcn_s_setprio(0);
  };

  // prologue: stage first pair (or single) into buf 0
  if (qt >= 1) stage2(0, 0); else stage1(0, 0);

  int cur = 0;
  int jp = 0;
  for (; jp + 1 <= qt; jp += 2) {
    // barrier #1: all waves done reading Ks[cur^1]
    asm volatile("" ::: "memory");
    __builtin_amdgcn_s_barrier();
    asm volatile("" ::: "memory");

    bf16x8 vfA[2][4];
    loadV(jp, vfA);                     // 8 V loads (oldest after oldK)
    asm volatile("" ::: "memory");      // pin V issue before K-DMA

    const int nx = jp + 2;
    if (nx + 1 <= qt) {
      stage2(nx, cur ^ 1);
      asm volatile("s_waitcnt vmcnt(12)" ::: "memory");  // drain oldK(4)
    } else if (nx <= qt) {
      stage1(nx, cur ^ 1);
      asm volatile("s_waitcnt vmcnt(10)" ::: "memory");
    } else {
      asm volatile("s_waitcnt vmcnt(8)" ::: "memory");
    }
    // barrier #2: every wave's pair-K DMAs have landed
    __builtin_amdgcn_s_barrier();
    asm volatile("" ::: "memory");

    // ---- tile A (index jp, never diagonal in pair loop) ----
    f32x4 accS[4];
    computeS(&Ks[cur][0], accS);
    softmaxStore(accS, false);
    pv(vfA);

    asm volatile("" ::: "memory");  // tile A P-reads before tile B P-writes

    // ---- tile B (index jp+1, diag iff == qt); sync-free ----
    bf16x8 vfB[2][4];
    loadV(jp + 1, vfB);             // hidden under S(B)+softmax(B)
    computeS(&Ks[cur][TEL_], accS);
    softmaxStore(accS, jp + 1 == qt);
    pv(vfB);

    cur ^= 1;
  }
  if (jp <= qt) {  // peeled single (diagonal) tile
    asm volatile("" ::: "memory");
    __builtin_amdgcn_s_barrier();
    asm volatile("" ::: "memory");
    bf16x8 vfA[2][4];
    loadV(jp, vfA);
    asm volatile("s_waitcnt vmcnt(8)" ::: "memory");  // drain the 2 oldK
    __builtin_amdgcn_s_barrier();
    asm volatile("" ::: "memory");
    f32x4 accS[4];
    computeS(&Ks[cur][0], accS);
    softmaxStore(accS, true);
    pv(vfA);
  }

  // ---- deferred row reduction + epilogue ----
  l_acc += __shfl_xor(l_acc, 16);
  l_acc += __shfl_xor(l_acc, 32);
  const float inv = (query == 0) ? 0.0f : 1.0f / l_acc;
  __hip_bfloat16* yb = y + ((size_t)b * T_ + query) * C_ + h * HS_;
#pragma unroll
  for (int mo = 0; mo < 4; ++mo) {
    int2 pkd;
    pkd.x = pack_bf16(accO[mo][0] * inv, accO[mo][1] * inv);
    pkd.y = pack_bf16(accO[mo][2] * inv, accO[mo][3] * inv);
    *reinterpret_cast<int2*>(yb + mo * 16 + kg * 4) = pkd;
  }
}

// ---------------------------------------------------------------------------
extern "C" void kernel_launch(void* const* d_in, const int* in_sizes, int n_in,
                              void* d_out, int out_size, void* d_ws, size_t ws_size,
                              hipStream_t stream) {
  const float* x           = (const float*)d_in[0];
  const float* W_la        = (const float*)d_in[1];
  const float* la_coef     = (const float*)d_in[2];
  const float* kernel_beta = (const float*)d_in[3];
  const float* value_beta  = (const float*)d_in[4];
  const float* W_v         = (const float*)d_in[5];
  const float* v_coef      = (const float*)d_in[6];
  const float* W_proj      = (const float*)d_in[7];
  float* out = (float*)d_out;

  char* wsb = (char*)d_ws;
  const size_t MB = 1024u * 1024u;
  __hip_bfloat16* x16    = (__hip_bfloat16*)(wsb);            // 8 MB
  __hip_bfloat16* Wcat   = (__hip_bfloat16*)(wsb + 8 * MB);   // 4 MB (W_laT | W_vT)
  __hip_bfloat16* WprojT = (__hip_bfloat16*)(wsb + 12 * MB);  // 2 MB
  float* xl              = (float*)(wsb + 16 * MB);           // 16 MB
  float* xv              = (float*)(wsb + 32 * MB);           // 16 MB
  __hip_bfloat16* kb16   = (__hip_bfloat16*)(wsb + 48 * MB);  // 8 MB
  __hip_bfloat16* vt16   = (__hip_bfloat16*)(wsb + 56 * MB);  // 8 MB
  __hip_bfloat16* y16    = (__hip_bfloat16*)(wsb + 64 * MB);  // 8 MB (xl still
                                                              //  live during prep2)
  (void)ws_size; (void)in_sizes; (void)n_in; (void)out_size;

  const int M = B_ * T_;

  prep1_kernel<<<dim3(2048 + 768), dim3(256), 0, stream>>>(x, W_la, W_v, W_proj, x16, Wcat, WprojT);
  gemm_in_kernel<<<dim3(2 * C_ / 128, M / 128), dim3(256), 0, stream>>>(x16, Wcat, xl, xv);
  prep2_kernel<<<dim3(1024 + 512), dim3(256), 0, stream>>>(xv, xl, vt16, kb16,
                                                           value_beta, v_coef, la_coef, kernel_beta);
  attn_mfma_kernel<<<dim3(8 * 128), dim3(256), 0, stream>>>(kb16, vt16, y16);
  gemm_proj_kernel<<<dim3(C_ / 128, M / 64), dim3(256), 0, stream>>>(y16, WprojT, out);
}

// Round 12
// 179.083 us; speedup vs baseline: 1.1323x; 1.0435x over previous
//
#include <hip/hip_runtime.h>
#include <hip/hip_bf16.h>

#define B_  2
#define T_  2048
#define NH_ 16
#define HS_ 64
#define C_  1024
#define SCL_ 128              // EMA chunk length
#define SCN_ (T_ / SCL_)      // 16 chunks
#define NT_  (T_ / 64)        // 32 key/query tiles
#define TEL_ 4096             // elements per 64x64 tile

typedef __attribute__((ext_vector_type(8))) short bf16x8;
typedef __attribute__((ext_vector_type(4))) float f32x4;

__device__ inline int pack_bf16(float a, float b) {
  union { __hip_bfloat16 h; unsigned short u; } ua, ub;
  ua.h = __float2bfloat16(a);
  ub.h = __float2bfloat16(b);
  return (int)(((unsigned)ub.u << 16) | (unsigned)ua.u);
}

// async global->LDS 16B: global ptr is PER-LANE; LDS dest must equal
// wave-uniform base + lane*16. Callers pass per-lane g AND l = base+lane*16.
__device__ inline void gl_lds16(const __hip_bfloat16* g, __hip_bfloat16* l) {
  __builtin_amdgcn_global_load_lds(
      (const __attribute__((address_space(1))) unsigned int*)g,
      (__attribute__((address_space(3))) unsigned int*)l, 16, 0, 0);
}

// ---------------------------------------------------------------------------
// prep1: fused {fp32->bf16 x conversion} + {3x weight transpose to bf16}.
// blocks [0,2048): cvt (8 elems/thread). blocks [2048,2816): cvtT (z = id>>8).
// ---------------------------------------------------------------------------
__global__ __launch_bounds__(256) void prep1_kernel(const float* __restrict__ x,
                                                    const float* __restrict__ W_la,
                                                    const float* __restrict__ W_v,
                                                    const float* __restrict__ W_proj,
                                                    __hip_bfloat16* __restrict__ x16,
                                                    __hip_bfloat16* __restrict__ Wcat,
                                                    __hip_bfloat16* __restrict__ WprojT) {
  __shared__ __hip_bfloat16 tile[64][66];
  const int bid = (int)blockIdx.x;
  if (bid < 2048) {
    const int i = (bid * 256 + (int)threadIdx.x) * 8;
    const float4 a = *reinterpret_cast<const float4*>(x + i);
    const float4 b = *reinterpret_cast<const float4*>(x + i + 4);
    union { int s[4]; int4 v; } u;
    u.s[0] = pack_bf16(a.x, a.y);
    u.s[1] = pack_bf16(a.z, a.w);
    u.s[2] = pack_bf16(b.x, b.y);
    u.s[3] = pack_bf16(b.z, b.w);
    *reinterpret_cast<int4*>(x16 + i) = u.v;
    return;
  }
  const int id = bid - 2048;        // 0..767
  const int z = id >> 8;            // 0..2
  const int rem = id & 255;
  const int bx = rem & 15, by = rem >> 4;
  const float* W = (z == 0) ? W_la : (z == 1) ? W_v : W_proj;
  __hip_bfloat16* WT = (z == 2) ? WprojT : Wcat + (size_t)z * C_ * C_;
  const int w = threadIdx.x >> 6, l = threadIdx.x & 63;
  const int n0 = bx * 64, k0 = by * 64;
#pragma unroll
  for (int r = 0; r < 16; ++r) {
    const int k = k0 + w * 16 + r;
    tile[w * 16 + r][l] = __float2bfloat16(W[(size_t)k * C_ + n0 + l]);
  }
  __syncthreads();
#pragma unroll
  for (int r = 0; r < 16; ++r) {
    const int nn = w * 16 + r;
    WT[(size_t)(n0 + nn) * C_ + k0 + l] = tile[l][nn];
  }
}

// ---------------------------------------------------------------------------
// Combined input GEMM: [xl | xv] = x16(4096x1024) @ Wcat(2048x1024)^T.
// PAIRED K-TILES (R5 attn technique): one barrier round serves BK=64
// (2 K-tiles, 8 DMAs, counted vmcnt(8)); both halves computed sync-free.
// Barrier count halved (16 rounds vs 32). LDS 64 KB -> 2 blocks/CU (grid is
// 2/CU anyway).
// ---------------------------------------------------------------------------
__global__ __launch_bounds__(256) void gemm_in_kernel(const __hip_bfloat16* __restrict__ A,
                                                      const __hip_bfloat16* __restrict__ BT,
                                                      float* __restrict__ C0,
                                                      float* __restrict__ C1) {
  __shared__ __hip_bfloat16 As[2][2 * 4096];  // 32 KB: [buf][ktile0|ktile1]
  __shared__ __hip_bfloat16 Bs[2][2 * 4096];  // 32 KB
  const int tid = threadIdx.x;
  const int m0 = blockIdx.y * 128, n0 = blockIdx.x * 128;
  const int w = tid >> 6, l = tid & 63;
  const int n = l & 15, kg = l >> 4;
  const int m0w = (w & 1) * 64, n0w = (w >> 1) * 64;

  const int r0 = tid >> 2, o0 = (tid & 3) * 8;
  const __hip_bfloat16* ag0 = A + (size_t)(m0 + r0) * C_ + o0;
  const __hip_bfloat16* ag1 = A + (size_t)(m0 + 64 + r0) * C_ + o0;
  const __hip_bfloat16* bg0 = BT + (size_t)(n0 + r0) * C_ + o0;
  const __hip_bfloat16* bg1 = BT + (size_t)(n0 + 64 + r0) * C_ + o0;

  f32x4 acc[4][4];
#pragma unroll
  for (int i = 0; i < 4; ++i)
#pragma unroll
    for (int j = 0; j < 4; ++j) acc[i][j] = f32x4{0.f, 0.f, 0.f, 0.f};

  auto stagePair = [&](int kk, int buf) {   // 8 DMAs: K-tiles kk, kk+32
    __hip_bfloat16* a = &As[buf][0];
    __hip_bfloat16* b = &Bs[buf][0];
#pragma unroll
    for (int hf = 0; hf < 2; ++hf) {
      gl_lds16(ag0 + kk + hf * 32, a + hf * 4096 + tid * 8);
      gl_lds16(ag1 + kk + hf * 32, a + hf * 4096 + 2048 + tid * 8);
      gl_lds16(bg0 + kk + hf * 32, b + hf * 4096 + tid * 8);
      gl_lds16(bg1 + kk + hf * 32, b + hf * 4096 + 2048 + tid * 8);
    }
  };

  stagePair(0, 0);
  int cur = 0;
  for (int kp = 0; kp < C_; kp += 64) {     // 16 paired rounds
    asm volatile("" ::: "memory");
    __builtin_amdgcn_s_barrier();   // buf[cur^1] readers (round-1) done
    asm volatile("" ::: "memory");
    if (kp + 64 < C_) {
      stagePair(kp + 64, cur ^ 1);
      asm volatile("s_waitcnt vmcnt(8)" ::: "memory");  // older 8 (this pair) landed
    } else {
      asm volatile("s_waitcnt vmcnt(0)" ::: "memory");
    }
    __builtin_amdgcn_s_barrier();   // all waves' pair DMAs landed
    asm volatile("" ::: "memory");

#pragma unroll
    for (int hf = 0; hf < 2; ++hf) {
      const __hip_bfloat16* Ab = &As[cur][hf * 4096];
      const __hip_bfloat16* Bb = &Bs[cur][hf * 4096];
      bf16x8 af[4], bf[4];
#pragma unroll
      for (int ms = 0; ms < 4; ++ms)
        af[ms] = *reinterpret_cast<const bf16x8*>(Ab + (m0w + ms * 16 + n) * 32 + kg * 8);
#pragma unroll
      for (int ns = 0; ns < 4; ++ns)
        bf[ns] = *reinterpret_cast<const bf16x8*>(Bb + (n0w + ns * 16 + n) * 32 + kg * 8);
#pragma unroll
      for (int ms = 0; ms < 4; ++ms)
#pragma unroll
        for (int ns = 0; ns < 4; ++ns)
          acc[ms][ns] = __builtin_amdgcn_mfma_f32_16x16x32_bf16(af[ms], bf[ns], acc[ms][ns], 0, 0, 0);
    }
    cur ^= 1;
  }

  float* Cb = (n0 < C_) ? C0 : C1;
  const int nc = (n0 < C_) ? n0 : n0 - C_;
#pragma unroll
  for (int ms = 0; ms < 4; ++ms) {
#pragma unroll
    for (int r = 0; r < 4; ++r) {
      const int row = m0 + m0w + ms * 16 + kg * 4 + r;
      float* cp = Cb + (size_t)row * C_ + nc + n0w + n;
#pragma unroll
      for (int ns = 0; ns < 4; ++ns) cp[ns * 16] = acc[ms][ns][r];
    }
  }
}

// ---------------------------------------------------------------------------
// Projection GEMM: out = y16(4096x1024) @ WprojT(1024x1024)^T, fp32 out.
// Same paired-K structure: 6 DMAs/pair, vmcnt(6). LDS 48 KB -> 3 blocks/CU.
// ---------------------------------------------------------------------------
__global__ __launch_bounds__(256) void gemm_proj_kernel(const __hip_bfloat16* __restrict__ A,
                                                        const __hip_bfloat16* __restrict__ BT,
                                                        float* __restrict__ Cout) {
  __shared__ __hip_bfloat16 As[2][2 * 2048];  // 16 KB
  __shared__ __hip_bfloat16 Bs[2][2 * 4096];  // 32 KB
  const int tid = threadIdx.x;
  const int m0 = blockIdx.y * 64, n0 = blockIdx.x * 128;
  const int w = tid >> 6, l = tid & 63;
  const int n = l & 15, kg = l >> 4;

  const int r0 = tid >> 2, o0 = (tid & 3) * 8;
  const __hip_bfloat16* ag = A + (size_t)(m0 + r0) * C_ + o0;
  const __hip_bfloat16* bg0 = BT + (size_t)(n0 + r0) * C_ + o0;
  const __hip_bfloat16* bg1 = BT + (size_t)(n0 + 64 + r0) * C_ + o0;

  f32x4 acc[4][2];
#pragma unroll
  for (int i = 0; i < 4; ++i)
#pragma unroll
    for (int j = 0; j < 2; ++j) acc[i][j] = f32x4{0.f, 0.f, 0.f, 0.f};

  auto stagePair = [&](int kk, int buf) {   // 6 DMAs: K-tiles kk, kk+32
    __hip_bfloat16* a = &As[buf][0];
    __hip_bfloat16* b = &Bs[buf][0];
#pragma unroll
    for (int hf = 0; hf < 2; ++hf) {
      gl_lds16(ag + kk + hf * 32, a + hf * 2048 + tid * 8);
      gl_lds16(bg0 + kk + hf * 32, b + hf * 4096 + tid * 8);
      gl_lds16(bg1 + kk + hf * 32, b + hf * 4096 + 2048 + tid * 8);
    }
  };

  stagePair(0, 0);
  int cur = 0;
  for (int kp = 0; kp < C_; kp += 64) {
    asm volatile("" ::: "memory");
    __builtin_amdgcn_s_barrier();
    asm volatile("" ::: "memory");
    if (kp + 64 < C_) {
      stagePair(kp + 64, cur ^ 1);
      asm volatile("s_waitcnt vmcnt(6)" ::: "memory");
    } else {
      asm volatile("s_waitcnt vmcnt(0)" ::: "memory");
    }
    __builtin_amdgcn_s_barrier();
    asm volatile("" ::: "memory");

#pragma unroll
    for (int hf = 0; hf < 2; ++hf) {
      const __hip_bfloat16* Ab = &As[cur][hf * 2048];
      const __hip_bfloat16* Bb = &Bs[cur][hf * 4096];
      bf16x8 af[4], bf[2];
#pragma unroll
      for (int ms = 0; ms < 4; ++ms)
        af[ms] = *reinterpret_cast<const bf16x8*>(Ab + (ms * 16 + n) * 32 + kg * 8);
#pragma unroll
      for (int ns = 0; ns < 2; ++ns)
        bf[ns] = *reinterpret_cast<const bf16x8*>(Bb + (w * 32 + ns * 16 + n) * 32 + kg * 8);
#pragma unroll
      for (int ms = 0; ms < 4; ++ms)
#pragma unroll
        for (int ns = 0; ns < 2; ++ns)
          acc[ms][ns] = __builtin_amdgcn_mfma_f32_16x16x32_bf16(af[ms], bf[ns], acc[ms][ns], 0, 0, 0);
    }
    cur ^= 1;
  }

#pragma unroll
  for (int ms = 0; ms < 4; ++ms) {
#pragma unroll
    for (int r = 0; r < 4; ++r) {
      const int row = m0 + ms * 16 + kg * 4 + r;
      float* cp = Cout + (size_t)row * C_ + n0 + w * 32 + n;
#pragma unroll
      for (int ns = 0; ns < 2; ++ns) cp[ns * 16] = acc[ms][ns][r];
    }
  }
}

// ---------------------------------------------------------------------------
// prep2, LOW-LDS VARIANT (17.7 KB -> 8 blocks/CU). vprep: stage 65 rows,
// compute into regs, overlay transpose tile on cache. EMA: 64-row half-chunk
// scans, 4-wave strips, a16/a64 Horner carries, truncated warmup (alpha^128).
// ---------------------------------------------------------------------------
__global__ __launch_bounds__(256) void prep2_kernel(const float* __restrict__ xv,
                                                    const float* __restrict__ xl,
                                                    __hip_bfloat16* __restrict__ vt,
                                                    __hip_bfloat16* __restrict__ kb16,
                                                    const float* __restrict__ value_beta,
                                                    const float* __restrict__ v_coef,
                                                    const float* __restrict__ la_coef,
                                                    const float* __restrict__ kernel_beta) {
  __shared__ float smemf[65 * 64];   // 16640 B (vprep cache / EMA 64-row buf)
  __shared__ float carrP[4][64];     // 1 KB strip carries
  const int bid = (int)blockIdx.x;
  const int tid = threadIdx.x;
  const int w = tid >> 6, l = tid & 63;

  if (bid < 1024) {
    // ---- vprep: LDS-staged, tile overlays cache after reg buffering ----
    float* cache = smemf;
    const int tc = bid % NT_;
    const int bh = bid / NT_;
    const int h = bh % NH_, b = bh / NH_;
    const int t0 = tc * 64;

    const float c = v_coef[h];
    const float vb = expf(value_beta[h] * 10.0f);

    const float4* xv4 = reinterpret_cast<const float4*>(xv);
    float4* cache4 = reinterpret_cast<float4*>(cache);
#pragma unroll
    for (int i = 0; i < 5; ++i) {
      const int idx = tid + i * 256;
      if (idx < 65 * 16) {
        const int row = idx >> 4, c4 = idx & 15;
        const int t = t0 + row;
        float4 v = {0.f, 0.f, 0.f, 0.f};
        if (t < T_) v = xv4[((size_t)b * T_ + t) * (C_ / 4) + h * (HS_ / 4) + c4];
        cache4[row * 16 + c4] = v;
      }
    }
    __syncthreads();

    // compute all 16 normalized bf16 values into registers
    unsigned short us[16];
#pragma unroll
    for (int r = 0; r < 16; ++r) {
      const int tl = w * 16 + r;
      const float cu = cache[tl * HS_ + l];
      const float nxt = cache[(tl + 1) * HS_ + l];
      float val = nxt * (1.0f - c) + cu * c;
      float ssum = val * val;
#pragma unroll
      for (int m = 32; m; m >>= 1) ssum += __shfl_xor(ssum, m);
      union { __hip_bfloat16 hh; unsigned short uu; } cvt;
      cvt.hh = __float2bfloat16(val * (vb / sqrtf(ssum)));
      us[r] = cvt.uu;
    }
    __syncthreads();  // ALL cache reads done -> safe to overlay tile

    __hip_bfloat16 (*tile)[66] = reinterpret_cast<__hip_bfloat16(*)[66]>(smemf);
#pragma unroll
    for (int r = 0; r < 16; ++r) {
      union { __hip_bfloat16 hh; unsigned short uu; } cvt;
      cvt.uu = us[r];
      tile[w * 16 + r][l] = cvt.hh;
    }
    __syncthreads();
    __hip_bfloat16* vtb = vt + (size_t)(bh * NT_ + tc) * TEL_;
    const int kk = l >> 3, j = l & 7;  // l = key
    for (int rr = 0; rr < 16; ++rr) {
      const int hs = w * 16 + rr;
      vtb[(kk * 64 + hs) * 8 + j] = tile[l][hs];
    }
    return;
  }
  // ---- EMA: half-chunk (64-row) scan, 16 KB buffer ----
  {
    float* buf = smemf;  // first 64*64 floats used
    const int idx = bid - 1024;
    const int c = idx % SCN_;
    const int bh = idx / SCN_;
    const int b = bh / NH_, h = bh % NH_;

    const float alpha = la_coef[h];
    const float onema = 1.0f - alpha;
    const float a16 = __powf(alpha, 16.0f);
    const float a32 = a16 * a16;
    const float a64 = a32 * a32;
    const float kbs = expf(fminf(kernel_beta[h] * 10.0f, 5.0f));
    const float4* src4 = reinterpret_cast<const float4*>(xl + (size_t)b * T_ * C_ + h * HS_);
    float4* buf4 = reinterpret_cast<float4*>(buf);

    auto stageHalf = [&](int t0s) {  // 64 rows from t0s
#pragma unroll
      for (int i = 0; i < 4; ++i) {
        const int ix = tid + i * 256;
        const int tt = ix >> 4, d4 = ix & 15;
        buf4[tt * 16 + d4] = src4[(size_t)(t0s + tt) * (C_ / 4) + d4];
      }
    };
    auto scan16 = [&]() -> float {   // zero-init scan of wave's 16-row strip
      float A = 0.0f;
      const float* bp = buf + (w * 16) * HS_ + l;
#pragma unroll 4
      for (int tt = 0; tt < 16; ++tt) A = alpha * A + onema * bp[tt * HS_];
      return A;
    };
    auto comb = [&]() -> float {     // combined carry of 64 rows (4 strips)
      return ((carrP[0][l] * a16 + carrP[1][l]) * a16 + carrP[2][l]) * a16 + carrP[3][l];
    };

    const int t0 = c * SCL_;
    float W = 0.0f;                  // state at chunk start (truncated hist)
    if (c > 0) {
      stageHalf(t0 - SCL_);
      __syncthreads();
      carrP[w][l] = scan16();
      __syncthreads();
      const float Cw0 = comb();
      stageHalf(t0 - SCL_ + 64);
      __syncthreads();
      carrP[w][l] = scan16();
      __syncthreads();
      W = a64 * Cw0 + comb();
    }

    __hip_bfloat16* kt = kb16 + (size_t)bh * NT_ * TEL_;
    const int g = l >> 3, j = l & 7;

    float Shalf = W;                 // state entering current half
#pragma unroll
    for (int hf = 0; hf < 2; ++hf) {
      __syncthreads();               // prior buf reads done before restage
      stageHalf(t0 + hf * 64);
      __syncthreads();
      carrP[w][l] = scan16();
      __syncthreads();
      const float Snext = a64 * Shalf + comb();   // state entering next half
      float P = Shalf;
#pragma unroll
      for (int j2 = 0; j2 < 3; ++j2)
        if (j2 < w) P = carrP[j2][l] + a16 * P;   // wave-uniform branch
      // pass 2: re-scan strip with init P -> exact values; fused norm+emit
      const float* bp = buf + (w * 16) * HS_ + l;
      float A = P;
      for (int rr = 0; rr < 16; ++rr) {
        A = alpha * A + onema * bp[rr * HS_];
        float ss = A * A;
#pragma unroll
        for (int m = 32; m; m >>= 1) ss += __shfl_xor(ss, m);
        const int t = t0 + hf * 64 + w * 16 + rr;
        const int tile = t >> 6, key = t & 63;
        kt[(size_t)tile * TEL_ + (g * 64 + key) * 8 + j] = __float2bfloat16(A * (kbs / sqrtf(ss)));
      }
      Shalf = Snext;
    }
  }
}

// ---------------------------------------------------------------------------
// MFMA flash attention, V-DIRECT + 2-TILE PAIRED iterations (R5 config:
// best measured). Ks = 2 buf x 2 tiles (32 KB) + Ps 8 KB = 40960 B ->
// 4 blocks/CU. Per pair: 2 barriers serve TWO 64-key tiles; tile B sync-free.
// vmcnt: outstanding at wait = oldK(4) + vfA(8) + newK(c) -> vmcnt(8+c).
// ---------------------------------------------------------------------------
__global__ __launch_bounds__(256, 4) void attn_mfma_kernel(
    const __hip_bfloat16* __restrict__ kb,   // (BH, NT, g, key, 8) slot tiles
    const __hip_bfloat16* __restrict__ vt,   // (BH, NT, kk, hs, 8) slot tiles
    __hip_bfloat16* __restrict__ y) {        // (B, T, C) bf16
  __shared__ __hip_bfloat16 Ks[2][2 * TEL_]; // 32 KB: [buf][tile0|tile1]
  __shared__ __hip_bfloat16 Ps[4][16 * 64];  // 8 KB, XOR-swizzled granules

  const int id = (int)blockIdx.x;
  const int xcd = id & 7;
  const int s = id >> 3;                 // 0..127
  const int bh = xcd + 8 * (s & 3);      // 32 bh, grouped 4 per XCD
  const int v = s >> 2;                  // 0..31
  const int qt = (v < 16) ? (31 - v) : (v - 16);  // balanced bijection
  const int b = bh / NH_, h = bh % NH_;
  const int q0 = qt * 64;
  const int w = threadIdx.x >> 6;
  const int l = threadIdx.x & 63;
  const int n = l & 15;
  const int kg = l >> 4;
  const int qq = w * 16 + n;             // within-tile query index
  const int query = q0 + qq;
  const int lo = l * 8;                  // per-lane 16B offset (elements)
  const int tb = bh * NT_;
  const int so = w * 1024 + lo;          // per-wave stage offset (elements)

  // Q B-fragments from global slot tile (once)
  bf16x8 qf0, qf1;
  {
    const __hip_bfloat16* qtile = kb + (size_t)(tb + qt) * TEL_;
    qf0 = *reinterpret_cast<const bf16x8*>(qtile + (kg * 64 + qq) * 8);
    qf1 = *reinterpret_cast<const bf16x8*>(qtile + ((kg + 4) * 64 + qq) * 8);
  }
  // per-lane V fragment base: fragment (ks,mo) at vbase + ks*2048 + mo*128
  const __hip_bfloat16* vbase = vt + (size_t)tb * TEL_ + (kg * 64 + n) * 8;

  f32x4 accO[4];
#pragma unroll
  for (int i = 0; i < 4; ++i) accO[i] = f32x4{0.f, 0.f, 0.f, 0.f};
  float l_acc = 0.0f;

  __hip_bfloat16* Pw = Ps[w];
  int* Pwi = reinterpret_cast<int*>(Pw);

  auto stage2 = [&](int j0, int buf) {   // 4 DMAs: tiles j0, j0+1
    const size_t tg = (size_t)(tb + j0) * TEL_;
    __hip_bfloat16* Kb = &Ks[buf][0];
    gl_lds16(kb + tg + so, Kb + so);
    gl_lds16(kb + tg + so + 512, Kb + so + 512);
    gl_lds16(kb + tg + TEL_ + so, Kb + TEL_ + so);
    gl_lds16(kb + tg + TEL_ + so + 512, Kb + TEL_ + so + 512);
  };
  auto stage1 = [&](int j0, int buf) {   // 2 DMAs: tile j0 into half 0
    const size_t tg = (size_t)(tb + j0) * TEL_;
    __hip_bfloat16* Kb = &Ks[buf][0];
    gl_lds16(kb + tg + so, Kb + so);
    gl_lds16(kb + tg + so + 512, Kb + so + 512);
  };
  auto loadV = [&](int jt, bf16x8 (&vf)[2][4]) {
    const __hip_bfloat16* vp = vbase + (size_t)jt * TEL_;
#pragma unroll
    for (int ks = 0; ks < 2; ++ks)
#pragma unroll
      for (int mo = 0; mo < 4; ++mo)
        vf[ks][mo] = *reinterpret_cast<const bf16x8*>(vp + ks * 2048 + mo * 128);
  };
  auto computeS = [&](const __hip_bfloat16* Kc, f32x4 (&accS)[4]) {
    __builtin_amdgcn_s_setprio(1);
#pragma unroll
    for (int ms = 0; ms < 4; ++ms) {
      bf16x8 a0 = *reinterpret_cast<const bf16x8*>(Kc + (kg * 64 + ms * 16 + n) * 8);
      bf16x8 a1 = *reinterpret_cast<const bf16x8*>(Kc + ((kg + 4) * 64 + ms * 16 + n) * 8);
      f32x4 z{0.f, 0.f, 0.f, 0.f};
      z = __builtin_amdgcn_mfma_f32_16x16x32_bf16(a0, qf0, z, 0, 0, 0);
      accS[ms] = __builtin_amdgcn_mfma_f32_16x16x32_bf16(a1, qf1, z, 0, 0, 0);
    }
    __builtin_amdgcn_s_setprio(0);
  };
  auto softmaxStore = [&](const f32x4 (&accS)[4], bool diag) {
    if (!diag) {
#pragma unroll
      for (int ms = 0; ms < 4; ++ms) {
        const float p0 = __expf(accS[ms][0]), p1 = __expf(accS[ms][1]);
        const float p2 = __expf(accS[ms][2]), p3 = __expf(accS[ms][3]);
        l_acc += p0 + p1 + p2 + p3;
        const int po = n * 32 + (((ms * 4 + kg) ^ n) << 1);
        int2 pw;
        pw.x = pack_bf16(p0, p1);
        pw.y = pack_bf16(p2, p3);
        *reinterpret_cast<int2*>(&Pwi[po]) = pw;
      }
    } else {
#pragma unroll
      for (int ms = 0; ms < 4; ++ms) {
        const int kbase = ms * 16 + kg * 4;
        float p[4];
#pragma unroll
        for (int r = 0; r < 4; ++r) {
          const float e = __expf(accS[ms][r]);
          p[r] = (kbase + r < qq) ? e : 0.0f;
          l_acc += p[r];
        }
        const int po = n * 32 + (((ms * 4 + kg) ^ n) << 1);
        int2 pw;
        pw.x = pack_bf16(p[0], p[1]);
        pw.y = pack_bf16(p[2], p[3]);
        *reinterpret_cast<int2*>(&Pwi[po]) = pw;
      }
    }
  };
  auto pv = [&](const bf16x8 (&vf)[2][4]) {
    __builtin_amdgcn_s_setprio(1);
#pragma unroll
    for (int ks = 0; ks < 2; ++ks) {
      union { ushort4 u[2]; bf16x8 vv; } pr;
      const int ga = (ks * 8 + kg * 2) ^ n;      // granule of keys kg*8+0..3
      const __hip_bfloat16* pp = Pw + n * 64;
      pr.u[0] = *reinterpret_cast<const ushort4*>(pp + ga * 4);
      pr.u[1] = *reinterpret_cast<const ushort4*>(pp + (ga ^ 1) * 4);
#pragma unroll
      for (int mo = 0; mo < 4; ++mo)
        accO[mo] = __builtin_amdgcn_mfma_f32_16x16x32_bf16(vf[ks][mo], pr.vv, accO[mo], 0, 0, 0);
    }
    __builtin_amdgcn_s_setprio(0);
  };

  // prologue: stage first pair (or single) into buf 0
  if (qt >= 1) stage2(0, 0); else stage1(0, 0);

  int cur = 0;
  int jp = 0;
  for (; jp + 1 <= qt; jp += 2) {
    // barrier #1: all waves done reading Ks[cur^1]
    asm volatile("" ::: "memory");
    __builtin_amdgcn_s_barrier();
    asm volatile("" ::: "memory");

    bf16x8 vfA[2][4];
    loadV(jp, vfA);                     // 8 V loads (oldest after oldK)
    asm volatile("" ::: "memory");      // pin V issue before K-DMA

    const int nx = jp + 2;
    if (nx + 1 <= qt) {
      stage2(nx, cur ^ 1);
      asm volatile("s_waitcnt vmcnt(12)" ::: "memory");  // drain oldK(4)
    } else if (nx <= qt) {
      stage1(nx, cur ^ 1);
      asm volatile("s_waitcnt vmcnt(10)" ::: "memory");
    } else {
      asm volatile("s_waitcnt vmcnt(8)" ::: "memory");
    }
    // barrier #2: every wave's pair-K DMAs have landed
    __builtin_amdgcn_s_barrier();
    asm volatile("" ::: "memory");

    // ---- tile A (index jp, never diagonal in pair loop) ----
    f32x4 accS[4];
    computeS(&Ks[cur][0], accS);
    softmaxStore(accS, false);
    pv(vfA);

    asm volatile("" ::: "memory");  // tile A P-reads before tile B P-writes

    // ---- tile B (index jp+1, diag iff == qt); sync-free ----
    bf16x8 vfB[2][4];
    loadV(jp + 1, vfB);             // hidden under S(B)+softmax(B)
    computeS(&Ks[cur][TEL_], accS);
    softmaxStore(accS, jp + 1 == qt);
    pv(vfB);

    cur ^= 1;
  }
  if (jp <= qt) {  // peeled single (diagonal) tile
    asm volatile("" ::: "memory");
    __builtin_amdgcn_s_barrier();
    asm volatile("" ::: "memory");
    bf16x8 vfA[2][4];
    loadV(jp, vfA);
    asm volatile("s_waitcnt vmcnt(8)" ::: "memory");  // drain the 2 oldK
    __builtin_amdgcn_s_barrier();
    asm volatile("" ::: "memory");
    f32x4 accS[4];
    computeS(&Ks[cur][0], accS);
    softmaxStore(accS, true);
    pv(vfA);
  }

  // ---- deferred row reduction + epilogue ----
  l_acc += __shfl_xor(l_acc, 16);
  l_acc += __shfl_xor(l_acc, 32);
  const float inv = (query == 0) ? 0.0f : 1.0f / l_acc;
  __hip_bfloat16* yb = y + ((size_t)b * T_ + query) * C_ + h * HS_;
#pragma unroll
  for (int mo = 0; mo < 4; ++mo) {
    int2 pkd;
    pkd.x = pack_bf16(accO[mo][0] * inv, accO[mo][1] * inv);
    pkd.y = pack_bf16(accO[mo][2] * inv, accO[mo][3] * inv);
    *reinterpret_cast<int2*>(yb + mo * 16 + kg * 4) = pkd;
  }
}

// ---------------------------------------------------------------------------
extern "C" void kernel_launch(void* const* d_in, const int* in_sizes, int n_in,
                              void* d_out, int out_size, void* d_ws, size_t ws_size,
                              hipStream_t stream) {
  const float* x           = (const float*)d_in[0];
  const float* W_la        = (const float*)d_in[1];
  const float* la_coef     = (const float*)d_in[2];
  const float* kernel_beta = (const float*)d_in[3];
  const float* value_beta  = (const float*)d_in[4];
  const float* W_v         = (const float*)d_in[5];
  const float* v_coef      = (const float*)d_in[6];
  const float* W_proj      = (const float*)d_in[7];
  float* out = (float*)d_out;

  char* wsb = (char*)d_ws;
  const size_t MB = 1024u * 1024u;
  __hip_bfloat16* x16    = (__hip_bfloat16*)(wsb);            // 8 MB
  __hip_bfloat16* Wcat   = (__hip_bfloat16*)(wsb + 8 * MB);   // 4 MB (W_laT | W_vT)
  __hip_bfloat16* WprojT = (__hip_bfloat16*)(wsb + 12 * MB);  // 2 MB
  float* xl              = (float*)(wsb + 16 * MB);           // 16 MB
  float* xv              = (float*)(wsb + 32 * MB);           // 16 MB
  __hip_bfloat16* kb16   = (__hip_bfloat16*)(wsb + 48 * MB);  // 8 MB
  __hip_bfloat16* vt16   = (__hip_bfloat16*)(wsb + 56 * MB);  // 8 MB
  __hip_bfloat16* y16    = (__hip_bfloat16*)(wsb + 64 * MB);  // 8 MB (xl still
                                                              //  live during prep2)
  (void)ws_size; (void)in_sizes; (void)n_in; (void)out_size;

  const int M = B_ * T_;

  prep1_kernel<<<dim3(2048 + 768), dim3(256), 0, stream>>>(x, W_la, W_v, W_proj, x16, Wcat, WprojT);
  gemm_in_kernel<<<dim3(2 * C_ / 128, M / 128), dim3(256), 0, stream>>>(x16, Wcat, xl, xv);
  prep2_kernel<<<dim3(1024 + 512), dim3(256), 0, stream>>>(xv, xl, vt16, kb16,
                                                           value_beta, v_coef, la_coef, kernel_beta);
  attn_mfma_kernel<<<dim3(8 * 128), dim3(256), 0, stream>>>(kb16, vt16, y16);
  gemm_proj_kernel<<<dim3(C_ / 128, M / 64), dim3(256), 0, stream>>>(y16, WprojT, out);
}

// Round 14
// 176.512 us; speedup vs baseline: 1.1488x; 1.0146x over previous
//
#include <hip/hip_runtime.h>
#include <hip/hip_bf16.h>

#define B_  2
#define T_  2048
#define NH_ 16
#define HS_ 64
#define C_  1024
#define SCL_ 128              // EMA chunk length
#define SCN_ (T_ / SCL_)      // 16 chunks
#define NT_  (T_ / 64)        // 32 key/query tiles
#define TEL_ 4096             // elements per 64x64 tile

typedef __attribute__((ext_vector_type(8))) short bf16x8;
typedef __attribute__((ext_vector_type(4))) float f32x4;

__device__ inline int pack_bf16(float a, float b) {
  union { __hip_bfloat16 h; unsigned short u; } ua, ub;
  ua.h = __float2bfloat16(a);
  ub.h = __float2bfloat16(b);
  return (int)(((unsigned)ub.u << 16) | (unsigned)ua.u);
}

__device__ inline void bf8_to_f32(const bf16x8 v, float* out) {
  union { bf16x8 vv; __hip_bfloat16 h[8]; } u;
  u.vv = v;
#pragma unroll
  for (int k = 0; k < 8; ++k) out[k] = __bfloat162float(u.h[k]);
}

// async global->LDS 16B: global ptr is PER-LANE; LDS dest must equal
// wave-uniform base + lane*16. Callers pass per-lane g AND l = base+lane*16.
__device__ inline void gl_lds16(const __hip_bfloat16* g, __hip_bfloat16* l) {
  __builtin_amdgcn_global_load_lds(
      (const __attribute__((address_space(1))) unsigned int*)g,
      (__attribute__((address_space(3))) unsigned int*)l, 16, 0, 0);
}

// ---------------------------------------------------------------------------
// prep1: fused {fp32->bf16 x conversion} + {3x weight transpose to bf16}.
// blocks [0,2048): cvt (8 elems/thread). blocks [2048,2816): cvtT (z = id>>8).
// ---------------------------------------------------------------------------
__global__ __launch_bounds__(256) void prep1_kernel(const float* __restrict__ x,
                                                    const float* __restrict__ W_la,
                                                    const float* __restrict__ W_v,
                                                    const float* __restrict__ W_proj,
                                                    __hip_bfloat16* __restrict__ x16,
                                                    __hip_bfloat16* __restrict__ Wcat,
                                                    __hip_bfloat16* __restrict__ WprojT) {
  __shared__ __hip_bfloat16 tile[64][66];
  const int bid = (int)blockIdx.x;
  if (bid < 2048) {
    const int i = (bid * 256 + (int)threadIdx.x) * 8;
    const float4 a = *reinterpret_cast<const float4*>(x + i);
    const float4 b = *reinterpret_cast<const float4*>(x + i + 4);
    union { int s[4]; int4 v; } u;
    u.s[0] = pack_bf16(a.x, a.y);
    u.s[1] = pack_bf16(a.z, a.w);
    u.s[2] = pack_bf16(b.x, b.y);
    u.s[3] = pack_bf16(b.z, b.w);
    *reinterpret_cast<int4*>(x16 + i) = u.v;
    return;
  }
  const int id = bid - 2048;        // 0..767
  const int z = id >> 8;            // 0..2
  const int rem = id & 255;
  const int bx = rem & 15, by = rem >> 4;
  const float* W = (z == 0) ? W_la : (z == 1) ? W_v : W_proj;
  __hip_bfloat16* WT = (z == 2) ? WprojT : Wcat + (size_t)z * C_ * C_;
  const int w = threadIdx.x >> 6, l = threadIdx.x & 63;
  const int n0 = bx * 64, k0 = by * 64;
#pragma unroll
  for (int r = 0; r < 16; ++r) {
    const int k = k0 + w * 16 + r;
    tile[w * 16 + r][l] = __float2bfloat16(W[(size_t)k * C_ + n0 + l]);
  }
  __syncthreads();
#pragma unroll
  for (int r = 0; r < 16; ++r) {
    const int nn = w * 16 + r;
    WT[(size_t)(n0 + nn) * C_ + k0 + l] = tile[l][nn];
  }
}

// ---------------------------------------------------------------------------
// Combined input GEMM: [xl16 | xv16] = x16(4096x1024) @ Wcat(2048x1024)^T.
// PAIRED K-TILES (BK=64, 8 DMAs/round, counted vmcnt(8)); BF16 OUTPUT
// (halves the 32 MB intermediate write + downstream reads; xl/xv are
// already bf16-rounded-input products and k/v get bf16-rounded anyway, so
// incremental error <= sqrt(2)x).
// ---------------------------------------------------------------------------
__global__ __launch_bounds__(256) void gemm_in_kernel(const __hip_bfloat16* __restrict__ A,
                                                      const __hip_bfloat16* __restrict__ BT,
                                                      __hip_bfloat16* __restrict__ C0,
                                                      __hip_bfloat16* __restrict__ C1) {
  __shared__ __hip_bfloat16 As[2][2 * 4096];  // 32 KB: [buf][ktile0|ktile1]
  __shared__ __hip_bfloat16 Bs[2][2 * 4096];  // 32 KB
  const int tid = threadIdx.x;
  const int m0 = blockIdx.y * 128, n0 = blockIdx.x * 128;
  const int w = tid >> 6, l = tid & 63;
  const int n = l & 15, kg = l >> 4;
  const int m0w = (w & 1) * 64, n0w = (w >> 1) * 64;

  const int r0 = tid >> 2, o0 = (tid & 3) * 8;
  const __hip_bfloat16* ag0 = A + (size_t)(m0 + r0) * C_ + o0;
  const __hip_bfloat16* ag1 = A + (size_t)(m0 + 64 + r0) * C_ + o0;
  const __hip_bfloat16* bg0 = BT + (size_t)(n0 + r0) * C_ + o0;
  const __hip_bfloat16* bg1 = BT + (size_t)(n0 + 64 + r0) * C_ + o0;

  f32x4 acc[4][4];
#pragma unroll
  for (int i = 0; i < 4; ++i)
#pragma unroll
    for (int j = 0; j < 4; ++j) acc[i][j] = f32x4{0.f, 0.f, 0.f, 0.f};

  auto stagePair = [&](int kk, int buf) {   // 8 DMAs: K-tiles kk, kk+32
    __hip_bfloat16* a = &As[buf][0];
    __hip_bfloat16* b = &Bs[buf][0];
#pragma unroll
    for (int hf = 0; hf < 2; ++hf) {
      gl_lds16(ag0 + kk + hf * 32, a + hf * 4096 + tid * 8);
      gl_lds16(ag1 + kk + hf * 32, a + hf * 4096 + 2048 + tid * 8);
      gl_lds16(bg0 + kk + hf * 32, b + hf * 4096 + tid * 8);
      gl_lds16(bg1 + kk + hf * 32, b + hf * 4096 + 2048 + tid * 8);
    }
  };

  stagePair(0, 0);
  int cur = 0;
  for (int kp = 0; kp < C_; kp += 64) {     // 16 paired rounds
    asm volatile("" ::: "memory");
    __builtin_amdgcn_s_barrier();   // buf[cur^1] readers (round-1) done
    asm volatile("" ::: "memory");
    if (kp + 64 < C_) {
      stagePair(kp + 64, cur ^ 1);
      asm volatile("s_waitcnt vmcnt(8)" ::: "memory");  // older 8 (this pair) landed
    } else {
      asm volatile("s_waitcnt vmcnt(0)" ::: "memory");
    }
    __builtin_amdgcn_s_barrier();   // all waves' pair DMAs landed
    asm volatile("" ::: "memory");

#pragma unroll
    for (int hf = 0; hf < 2; ++hf) {
      const __hip_bfloat16* Ab = &As[cur][hf * 4096];
      const __hip_bfloat16* Bb = &Bs[cur][hf * 4096];
      bf16x8 af[4], bf[4];
#pragma unroll
      for (int ms = 0; ms < 4; ++ms)
        af[ms] = *reinterpret_cast<const bf16x8*>(Ab + (m0w + ms * 16 + n) * 32 + kg * 8);
#pragma unroll
      for (int ns = 0; ns < 4; ++ns)
        bf[ns] = *reinterpret_cast<const bf16x8*>(Bb + (n0w + ns * 16 + n) * 32 + kg * 8);
#pragma unroll
      for (int ms = 0; ms < 4; ++ms)
#pragma unroll
        for (int ns = 0; ns < 4; ++ns)
          acc[ms][ns] = __builtin_amdgcn_mfma_f32_16x16x32_bf16(af[ms], bf[ns], acc[ms][ns], 0, 0, 0);
    }
    cur ^= 1;
  }

  __hip_bfloat16* Cb = (n0 < C_) ? C0 : C1;
  const int nc = (n0 < C_) ? n0 : n0 - C_;
#pragma unroll
  for (int ms = 0; ms < 4; ++ms) {
#pragma unroll
    for (int r = 0; r < 4; ++r) {
      const int row = m0 + m0w + ms * 16 + kg * 4 + r;
      __hip_bfloat16* cp = Cb + (size_t)row * C_ + nc + n0w + n;
#pragma unroll
      for (int ns = 0; ns < 4; ++ns) cp[ns * 16] = __float2bfloat16(acc[ms][ns][r]);
    }
  }
}

// ---------------------------------------------------------------------------
// Projection GEMM: out = y16(4096x1024) @ WprojT(1024x1024)^T, fp32 out.
// Paired-K structure: 6 DMAs/pair, vmcnt(6). LDS 48 KB -> 3 blocks/CU.
// ---------------------------------------------------------------------------
__global__ __launch_bounds__(256) void gemm_proj_kernel(const __hip_bfloat16* __restrict__ A,
                                                        const __hip_bfloat16* __restrict__ BT,
                                                        float* __restrict__ Cout) {
  __shared__ __hip_bfloat16 As[2][2 * 2048];  // 16 KB
  __shared__ __hip_bfloat16 Bs[2][2 * 4096];  // 32 KB
  const int tid = threadIdx.x;
  const int m0 = blockIdx.y * 64, n0 = blockIdx.x * 128;
  const int w = tid >> 6, l = tid & 63;
  const int n = l & 15, kg = l >> 4;

  const int r0 = tid >> 2, o0 = (tid & 3) * 8;
  const __hip_bfloat16* ag = A + (size_t)(m0 + r0) * C_ + o0;
  const __hip_bfloat16* bg0 = BT + (size_t)(n0 + r0) * C_ + o0;
  const __hip_bfloat16* bg1 = BT + (size_t)(n0 + 64 + r0) * C_ + o0;

  f32x4 acc[4][2];
#pragma unroll
  for (int i = 0; i < 4; ++i)
#pragma unroll
    for (int j = 0; j < 2; ++j) acc[i][j] = f32x4{0.f, 0.f, 0.f, 0.f};

  auto stagePair = [&](int kk, int buf) {   // 6 DMAs: K-tiles kk, kk+32
    __hip_bfloat16* a = &As[buf][0];
    __hip_bfloat16* b = &Bs[buf][0];
#pragma unroll
    for (int hf = 0; hf < 2; ++hf) {
      gl_lds16(ag + kk + hf * 32, a + hf * 2048 + tid * 8);
      gl_lds16(bg0 + kk + hf * 32, b + hf * 4096 + tid * 8);
      gl_lds16(bg1 + kk + hf * 32, b + hf * 4096 + 2048 + tid * 8);
    }
  };

  stagePair(0, 0);
  int cur = 0;
  for (int kp = 0; kp < C_; kp += 64) {
    asm volatile("" ::: "memory");
    __builtin_amdgcn_s_barrier();
    asm volatile("" ::: "memory");
    if (kp + 64 < C_) {
      stagePair(kp + 64, cur ^ 1);
      asm volatile("s_waitcnt vmcnt(6)" ::: "memory");
    } else {
      asm volatile("s_waitcnt vmcnt(0)" ::: "memory");
    }
    __builtin_amdgcn_s_barrier();
    asm volatile("" ::: "memory");

#pragma unroll
    for (int hf = 0; hf < 2; ++hf) {
      const __hip_bfloat16* Ab = &As[cur][hf * 2048];
      const __hip_bfloat16* Bb = &Bs[cur][hf * 4096];
      bf16x8 af[4], bf[2];
#pragma unroll
      for (int ms = 0; ms < 4; ++ms)
        af[ms] = *reinterpret_cast<const bf16x8*>(Ab + (ms * 16 + n) * 32 + kg * 8);
#pragma unroll
      for (int ns = 0; ns < 2; ++ns)
        bf[ns] = *reinterpret_cast<const bf16x8*>(Bb + (w * 32 + ns * 16 + n) * 32 + kg * 8);
#pragma unroll
      for (int ms = 0; ms < 4; ++ms)
#pragma unroll
        for (int ns = 0; ns < 2; ++ns)
          acc[ms][ns] = __builtin_amdgcn_mfma_f32_16x16x32_bf16(af[ms], bf[ns], acc[ms][ns], 0, 0, 0);
    }
    cur ^= 1;
  }

#pragma unroll
  for (int ms = 0; ms < 4; ++ms) {
#pragma unroll
    for (int r = 0; r < 4; ++r) {
      const int row = m0 + ms * 16 + kg * 4 + r;
      float* cp = Cout + (size_t)row * C_ + n0 + w * 32 + n;
#pragma unroll
      for (int ns = 0; ns < 2; ++ns) cp[ns * 16] = acc[ms][ns][r];
    }
  }
}

// ---------------------------------------------------------------------------
// prep2, LOW-LDS (17.7 KB, 8 blocks/CU), BF16 xl/xv inputs (conversion to
// f32 happens during LDS staging -- parallel work, NOT in the serial scan
// chain; scans/normalize still run on f32 LDS).
// vprep (blocks [0,1024)): stage 65 rows, compute into regs, overlay tile.
// EMA (blocks [1024,1536)): 64-row half-chunk scans, 4-wave 16-row strips,
// a16/a64 Horner carries, truncated warmup (alpha^128 <= 1.4e-6).
// ---------------------------------------------------------------------------
__global__ __launch_bounds__(256) void prep2_kernel(const __hip_bfloat16* __restrict__ xv,
                                                    const __hip_bfloat16* __restrict__ xl,
                                                    __hip_bfloat16* __restrict__ vt,
                                                    __hip_bfloat16* __restrict__ kb16,
                                                    const float* __restrict__ value_beta,
                                                    const float* __restrict__ v_coef,
                                                    const float* __restrict__ la_coef,
                                                    const float* __restrict__ kernel_beta) {
  __shared__ float smemf[65 * 64];   // 16640 B (vprep cache / EMA 64-row buf)
  __shared__ float carrP[4][64];     // 1 KB strip carries
  const int bid = (int)blockIdx.x;
  const int tid = threadIdx.x;
  const int w = tid >> 6, l = tid & 63;

  if (bid < 1024) {
    // ---- vprep: bf16-staged -> f32 cache; tile overlays cache after regs ----
    float* cache = smemf;
    const int tc = bid % NT_;
    const int bh = bid / NT_;
    const int h = bh % NH_, b = bh / NH_;
    const int t0 = tc * 64;

    const float c = v_coef[h];
    const float vb = expf(value_beta[h] * 10.0f);

    const __hip_bfloat16* xvb = xv + (size_t)b * T_ * C_ + h * HS_;
    float4* cache4 = reinterpret_cast<float4*>(cache);
#pragma unroll
    for (int i = 0; i < 3; ++i) {
      const int idx = tid + i * 256;        // 65 rows x 8 chunks = 520
      if (idx < 65 * 8) {
        const int row = idx >> 3, c8 = idx & 7;
        const int t = t0 + row;
        float f[8] = {0.f, 0.f, 0.f, 0.f, 0.f, 0.f, 0.f, 0.f};
        if (t < T_) {
          bf16x8 v = *reinterpret_cast<const bf16x8*>(xvb + (size_t)t * C_ + c8 * 8);
          bf8_to_f32(v, f);
        }
        cache4[row * 16 + c8 * 2]     = float4{f[0], f[1], f[2], f[3]};
        cache4[row * 16 + c8 * 2 + 1] = float4{f[4], f[5], f[6], f[7]};
      }
    }
    __syncthreads();

    // compute all 16 normalized bf16 values into registers
    unsigned short us[16];
#pragma unroll
    for (int r = 0; r < 16; ++r) {
      const int tl = w * 16 + r;
      const float cu = cache[tl * HS_ + l];
      const float nxt = cache[(tl + 1) * HS_ + l];
      float val = nxt * (1.0f - c) + cu * c;
      float ssum = val * val;
#pragma unroll
      for (int m = 32; m; m >>= 1) ssum += __shfl_xor(ssum, m);
      union { __hip_bfloat16 hh; unsigned short uu; } cvt;
      cvt.hh = __float2bfloat16(val * (vb / sqrtf(ssum)));
      us[r] = cvt.uu;
    }
    __syncthreads();  // ALL cache reads done -> safe to overlay tile

    __hip_bfloat16 (*tile)[66] = reinterpret_cast<__hip_bfloat16(*)[66]>(smemf);
#pragma unroll
    for (int r = 0; r < 16; ++r) {
      union { __hip_bfloat16 hh; unsigned short uu; } cvt;
      cvt.uu = us[r];
      tile[w * 16 + r][l] = cvt.hh;
    }
    __syncthreads();
    __hip_bfloat16* vtb = vt + (size_t)(bh * NT_ + tc) * TEL_;
    const int kk = l >> 3, j = l & 7;  // l = key
    for (int rr = 0; rr < 16; ++rr) {
      const int hs = w * 16 + rr;
      vtb[(kk * 64 + hs) * 8 + j] = tile[l][hs];
    }
    return;
  }
  // ---- EMA: half-chunk (64-row) scan, bf16 input staged to f32 LDS ----
  {
    float* buf = smemf;  // first 64*64 floats used
    const int idx = bid - 1024;
    const int c = idx % SCN_;
    const int bh = idx / SCN_;
    const int b = bh / NH_, h = bh % NH_;

    const float alpha = la_coef[h];
    const float onema = 1.0f - alpha;
    const float a16 = __powf(alpha, 16.0f);
    const float a32 = a16 * a16;
    const float a64 = a32 * a32;
    const float kbs = expf(fminf(kernel_beta[h] * 10.0f, 5.0f));
    const __hip_bfloat16* xlb = xl + (size_t)b * T_ * C_ + h * HS_;
    float4* buf4 = reinterpret_cast<float4*>(buf);

    auto stageHalf = [&](int t0s) {  // 64 rows from t0s (bf16 -> f32)
#pragma unroll
      for (int i = 0; i < 2; ++i) {
        const int ix = tid + i * 256;        // 64 rows x 8 chunks = 512
        const int tt = ix >> 3, c8 = ix & 7;
        bf16x8 v = *reinterpret_cast<const bf16x8*>(xlb + (size_t)(t0s + tt) * C_ + c8 * 8);
        float f[8];
        bf8_to_f32(v, f);
        buf4[tt * 16 + c8 * 2]     = float4{f[0], f[1], f[2], f[3]};
        buf4[tt * 16 + c8 * 2 + 1] = float4{f[4], f[5], f[6], f[7]};
      }
    };
    auto scan16 = [&]() -> float {   // zero-init scan of wave's 16-row strip
      float A = 0.0f;
      const float* bp = buf + (w * 16) * HS_ + l;
#pragma unroll 4
      for (int tt = 0; tt < 16; ++tt) A = alpha * A + onema * bp[tt * HS_];
      return A;
    };
    auto comb = [&]() -> float {     // combined carry of 64 rows (4 strips)
      return ((carrP[0][l] * a16 + carrP[1][l]) * a16 + carrP[2][l]) * a16 + carrP[3][l];
    };

    const int t0 = c * SCL_;
    float W = 0.0f;                  // state at chunk start (truncated hist)
    if (c > 0) {
      stageHalf(t0 - SCL_);
      __syncthreads();
      carrP[w][l] = scan16();
      __syncthreads();
      const float Cw0 = comb();
      stageHalf(t0 - SCL_ + 64);
      __syncthreads();
      carrP[w][l] = scan16();
      __syncthreads();
      W = a64 * Cw0 + comb();
    }

    __hip_bfloat16* kt = kb16 + (size_t)bh * NT_ * TEL_;
    const int g = l >> 3, j = l & 7;

    float Shalf = W;                 // state entering current half
#pragma unroll
    for (int hf = 0; hf < 2; ++hf) {
      __syncthreads();               // prior buf reads done before restage
      stageHalf(t0 + hf * 64);
      __syncthreads();
      carrP[w][l] = scan16();
      __syncthreads();
      const float Snext = a64 * Shalf + comb();   // state entering next half
      float P = Shalf;
#pragma unroll
      for (int j2 = 0; j2 < 3; ++j2)
        if (j2 < w) P = carrP[j2][l] + a16 * P;   // wave-uniform branch
      // pass 2: re-scan strip with init P -> exact values; fused norm+emit
      const float* bp = buf + (w * 16) * HS_ + l;
      float A = P;
      for (int rr = 0; rr < 16; ++rr) {
        A = alpha * A + onema * bp[rr * HS_];
        float ss = A * A;
#pragma unroll
        for (int m = 32; m; m >>= 1) ss += __shfl_xor(ss, m);
        const int t = t0 + hf * 64 + w * 16 + rr;
        const int tile = t >> 6, key = t & 63;
        kt[(size_t)tile * TEL_ + (g * 64 + key) * 8 + j] = __float2bfloat16(A * (kbs / sqrtf(ss)));
      }
      Shalf = Snext;
    }
  }
}

// ---------------------------------------------------------------------------
// MFMA flash attention, V-DIRECT + 2-TILE PAIRED iterations (R5 config:
// best measured). Ks = 2 buf x 2 tiles (32 KB) + Ps 8 KB = 40960 B ->
// 4 blocks/CU. Per pair: 2 barriers serve TWO 64-key tiles; tile B sync-free.
// vmcnt: outstanding at wait = oldK(4) + vfA(8) + newK(c) -> vmcnt(8+c).
// ---------------------------------------------------------------------------
__global__ __launch_bounds__(256, 4) void attn_mfma_kernel(
    const __hip_bfloat16* __restrict__ kb,   // (BH, NT, g, key, 8) slot tiles
    const __hip_bfloat16* __restrict__ vt,   // (BH, NT, kk, hs, 8) slot tiles
    __hip_bfloat16* __restrict__ y) {        // (B, T, C) bf16
  __shared__ __hip_bfloat16 Ks[2][2 * TEL_]; // 32 KB: [buf][tile0|tile1]
  __shared__ __hip_bfloat16 Ps[4][16 * 64];  // 8 KB, XOR-swizzled granules

  const int id = (int)blockIdx.x;
  const int xcd = id & 7;
  const int s = id >> 3;                 // 0..127
  const int bh = xcd + 8 * (s & 3);      // 32 bh, grouped 4 per XCD
  const int v = s >> 2;                  // 0..31
  const int qt = (v < 16) ? (31 - v) : (v - 16);  // balanced bijection
  const int b = bh / NH_, h = bh % NH_;
  const int q0 = qt * 64;
  const int w = threadIdx.x >> 6;
  const int l = threadIdx.x & 63;
  const int n = l & 15;
  const int kg = l >> 4;
  const int qq = w * 16 + n;             // within-tile query index
  const int query = q0 + qq;
  const int lo = l * 8;                  // per-lane 16B offset (elements)
  const int tb = bh * NT_;
  const int so = w * 1024 + lo;          // per-wave stage offset (elements)

  // Q B-fragments from global slot tile (once)
  bf16x8 qf0, qf1;
  {
    const __hip_bfloat16* qtile = kb + (size_t)(tb + qt) * TEL_;
    qf0 = *reinterpret_cast<const bf16x8*>(qtile + (kg * 64 + qq) * 8);
    qf1 = *reinterpret_cast<const bf16x8*>(qtile + ((kg + 4) * 64 + qq) * 8);
  }
  // per-lane V fragment base: fragment (ks,mo) at vbase + ks*2048 + mo*128
  const __hip_bfloat16* vbase = vt + (size_t)tb * TEL_ + (kg * 64 + n) * 8;

  f32x4 accO[4];
#pragma unroll
  for (int i = 0; i < 4; ++i) accO[i] = f32x4{0.f, 0.f, 0.f, 0.f};
  float l_acc = 0.0f;

  __hip_bfloat16* Pw = Ps[w];
  int* Pwi = reinterpret_cast<int*>(Pw);

  auto stage2 = [&](int j0, int buf) {   // 4 DMAs: tiles j0, j0+1
    const size_t tg = (size_t)(tb + j0) * TEL_;
    __hip_bfloat16* Kb = &Ks[buf][0];
    gl_lds16(kb + tg + so, Kb + so);
    gl_lds16(kb + tg + so + 512, Kb + so + 512);
    gl_lds16(kb + tg + TEL_ + so, Kb + TEL_ + so);
    gl_lds16(kb + tg + TEL_ + so + 512, Kb + TEL_ + so + 512);
  };
  auto stage1 = [&](int j0, int buf) {   // 2 DMAs: tile j0 into half 0
    const size_t tg = (size_t)(tb + j0) * TEL_;
    __hip_bfloat16* Kb = &Ks[buf][0];
    gl_lds16(kb + tg + so, Kb + so);
    gl_lds16(kb + tg + so + 512, Kb + so + 512);
  };
  auto loadV = [&](int jt, bf16x8 (&vf)[2][4]) {
    const __hip_bfloat16* vp = vbase + (size_t)jt * TEL_;
#pragma unroll
    for (int ks = 0; ks < 2; ++ks)
#pragma unroll
      for (int mo = 0; mo < 4; ++mo)
        vf[ks][mo] = *reinterpret_cast<const bf16x8*>(vp + ks * 2048 + mo * 128);
  };
  auto computeS = [&](const __hip_bfloat16* Kc, f32x4 (&accS)[4]) {
    __builtin_amdgcn_s_setprio(1);
#pragma unroll
    for (int ms = 0; ms < 4; ++ms) {
      bf16x8 a0 = *reinterpret_cast<const bf16x8*>(Kc + (kg * 64 + ms * 16 + n) * 8);
      bf16x8 a1 = *reinterpret_cast<const bf16x8*>(Kc + ((kg + 4) * 64 + ms * 16 + n) * 8);
      f32x4 z{0.f, 0.f, 0.f, 0.f};
      z = __builtin_amdgcn_mfma_f32_16x16x32_bf16(a0, qf0, z, 0, 0, 0);
      accS[ms] = __builtin_amdgcn_mfma_f32_16x16x32_bf16(a1, qf1, z, 0, 0, 0);
    }
    __builtin_amdgcn_s_setprio(0);
  };
  auto softmaxStore = [&](const f32x4 (&accS)[4], bool diag) {
    if (!diag) {
#pragma unroll
      for (int ms = 0; ms < 4; ++ms) {
        const float p0 = __expf(accS[ms][0]), p1 = __expf(accS[ms][1]);
        const float p2 = __expf(accS[ms][2]), p3 = __expf(accS[ms][3]);
        l_acc += p0 + p1 + p2 + p3;
        const int po = n * 32 + (((ms * 4 + kg) ^ n) << 1);
        int2 pw;
        pw.x = pack_bf16(p0, p1);
        pw.y = pack_bf16(p2, p3);
        *reinterpret_cast<int2*>(&Pwi[po]) = pw;
      }
    } else {
#pragma unroll
      for (int ms = 0; ms < 4; ++ms) {
        const int kbase = ms * 16 + kg * 4;
        float p[4];
#pragma unroll
        for (int r = 0; r < 4; ++r) {
          const float e = __expf(accS[ms][r]);
          p[r] = (kbase + r < qq) ? e : 0.0f;
          l_acc += p[r];
        }
        const int po = n * 32 + (((ms * 4 + kg) ^ n) << 1);
        int2 pw;
        pw.x = pack_bf16(p[0], p[1]);
        pw.y = pack_bf16(p[2], p[3]);
        *reinterpret_cast<int2*>(&Pwi[po]) = pw;
      }
    }
  };
  auto pv = [&](const bf16x8 (&vf)[2][4]) {
    __builtin_amdgcn_s_setprio(1);
#pragma unroll
    for (int ks = 0; ks < 2; ++ks) {
      union { ushort4 u[2]; bf16x8 vv; } pr;
      const int ga = (ks * 8 + kg * 2) ^ n;      // granule of keys kg*8+0..3
      const __hip_bfloat16* pp = Pw + n * 64;
      pr.u[0] = *reinterpret_cast<const ushort4*>(pp + ga * 4);
      pr.u[1] = *reinterpret_cast<const ushort4*>(pp + (ga ^ 1) * 4);
#pragma unroll
      for (int mo = 0; mo < 4; ++mo)
        accO[mo] = __builtin_amdgcn_mfma_f32_16x16x32_bf16(vf[ks][mo], pr.vv, accO[mo], 0, 0, 0);
    }
    __builtin_amdgcn_s_setprio(0);
  };

  // prologue: stage first pair (or single) into buf 0
  if (qt >= 1) stage2(0, 0); else stage1(0, 0);

  int cur = 0;
  int jp = 0;
  for (; jp + 1 <= qt; jp += 2) {
    // barrier #1: all waves done reading Ks[cur^1]
    asm volatile("" ::: "memory");
    __builtin_amdgcn_s_barrier();
    asm volatile("" ::: "memory");

    bf16x8 vfA[2][4];
    loadV(jp, vfA);                     // 8 V loads (oldest after oldK)
    asm volatile("" ::: "memory");      // pin V issue before K-DMA

    const int nx = jp + 2;
    if (nx + 1 <= qt) {
      stage2(nx, cur ^ 1);
      asm volatile("s_waitcnt vmcnt(12)" ::: "memory");  // drain oldK(4)
    } else if (nx <= qt) {
      stage1(nx, cur ^ 1);
      asm volatile("s_waitcnt vmcnt(10)" ::: "memory");
    } else {
      asm volatile("s_waitcnt vmcnt(8)" ::: "memory");
    }
    // barrier #2: every wave's pair-K DMAs have landed
    __builtin_amdgcn_s_barrier();
    asm volatile("" ::: "memory");

    // ---- tile A (index jp, never diagonal in pair loop) ----
    f32x4 accS[4];
    computeS(&Ks[cur][0], accS);
    softmaxStore(accS, false);
    pv(vfA);

    asm volatile("" ::: "memory");  // tile A P-reads before tile B P-writes

    // ---- tile B (index jp+1, diag iff == qt); sync-free ----
    bf16x8 vfB[2][4];
    loadV(jp + 1, vfB);             // hidden under S(B)+softmax(B)
    computeS(&Ks[cur][TEL_], accS);
    softmaxStore(accS, jp + 1 == qt);
    pv(vfB);

    cur ^= 1;
  }
  if (jp <= qt) {  // peeled single (diagonal) tile
    asm volatile("" ::: "memory");
    __builtin_amdgcn_s_barrier();
    asm volatile("" ::: "memory");
    bf16x8 vfA[2][4];
    loadV(jp, vfA);
    asm volatile("s_waitcnt vmcnt(8)" ::: "memory");  // drain the 2 oldK
    __builtin_amdgcn_s_barrier();
    asm volatile("" ::: "memory");
    f32x4 accS[4];
    computeS(&Ks[cur][0], accS);
    softmaxStore(accS, true);
    pv(vfA);
  }

  // ---- deferred row reduction + epilogue ----
  l_acc += __shfl_xor(l_acc, 16);
  l_acc += __shfl_xor(l_acc, 32);
  const float inv = (query == 0) ? 0.0f : 1.0f / l_acc;
  __hip_bfloat16* yb = y + ((size_t)b * T_ + query) * C_ + h * HS_;
#pragma unroll
  for (int mo = 0; mo < 4; ++mo) {
    int2 pkd;
    pkd.x = pack_bf16(accO[mo][0] * inv, accO[mo][1] * inv);
    pkd.y = pack_bf16(accO[mo][2] * inv, accO[mo][3] * inv);
    *reinterpret_cast<int2*>(yb + mo * 16 + kg * 4) = pkd;
  }
}

// ---------------------------------------------------------------------------
extern "C" void kernel_launch(void* const* d_in, const int* in_sizes, int n_in,
                              void* d_out, int out_size, void* d_ws, size_t ws_size,
                              hipStream_t stream) {
  const float* x           = (const float*)d_in[0];
  const float* W_la        = (const float*)d_in[1];
  const float* la_coef     = (const float*)d_in[2];
  const float* kernel_beta = (const float*)d_in[3];
  const float* value_beta  = (const float*)d_in[4];
  const float* W_v         = (const float*)d_in[5];
  const float* v_coef      = (const float*)d_in[6];
  const float* W_proj      = (const float*)d_in[7];
  float* out = (float*)d_out;

  char* wsb = (char*)d_ws;
  const size_t MB = 1024u * 1024u;
  __hip_bfloat16* x16    = (__hip_bfloat16*)(wsb);            // 8 MB
  __hip_bfloat16* Wcat   = (__hip_bfloat16*)(wsb + 8 * MB);   // 4 MB (W_laT | W_vT)
  __hip_bfloat16* WprojT = (__hip_bfloat16*)(wsb + 12 * MB);  // 2 MB
  __hip_bfloat16* xl16   = (__hip_bfloat16*)(wsb + 16 * MB);  // 8 MB (bf16 now)
  __hip_bfloat16* xv16   = (__hip_bfloat16*)(wsb + 24 * MB);  // 8 MB (bf16 now)
  __hip_bfloat16* y16    = (__hip_bfloat16*)(wsb + 32 * MB);  // 8 MB
  __hip_bfloat16* kb16   = (__hip_bfloat16*)(wsb + 48 * MB);  // 8 MB
  __hip_bfloat16* vt16   = (__hip_bfloat16*)(wsb + 56 * MB);  // 8 MB
  (void)ws_size; (void)in_sizes; (void)n_in; (void)out_size;

  const int M = B_ * T_;

  prep1_kernel<<<dim3(2048 + 768), dim3(256), 0, stream>>>(x, W_la, W_v, W_proj, x16, Wcat, WprojT);
  gemm_in_kernel<<<dim3(2 * C_ / 128, M / 128), dim3(256), 0, stream>>>(x16, Wcat, xl16, xv16);
  prep2_kernel<<<dim3(1024 + 512), dim3(256), 0, stream>>>(xv16, xl16, vt16, kb16,
                                                           value_beta, v_coef, la_coef, kernel_beta);
  attn_mfma_kernel<<<dim3(8 * 128), dim3(256), 0, stream>>>(kb16, vt16, y16);
  gemm_proj_kernel<<<dim3(C_ / 128, M / 64), dim3(256), 0, stream>>>(y16, WprojT, out);
}